// Round 8
// baseline (199.935 us; speedup 1.0000x reference)
//
#include <hip/hip_runtime.h>

typedef __attribute__((ext_vector_type(8))) short bf16x8;
typedef __attribute__((ext_vector_type(4))) float f32x4;

// Problem constants (from reference)
constexpr int B    = 8;
constexpr int N    = 4096;
constexpr int FIN  = 128;
constexpr int NT   = B * N;        // 32768
constexpr int H    = 4;
constexpr int C    = 64;
constexpr int D1   = H * C;        // 256
constexpr int E    = 524288;
constexpr int ETOT = E + NT;       // 557056
constexpr int NTILES = 18;         // 288 padded N: 256 xp | 4 asrc | 4 adst | 24 zero
constexpr int CAP  = 64;           // adjacency bucket capacity (max deg ~40, pad <= 48)

// bf16 round-to-nearest-even helpers
__device__ __forceinline__ unsigned short f2bf(float f) {
    unsigned u = __float_as_uint(f);
    return (unsigned short)((u + 0x7FFFu + ((u >> 16) & 1u)) >> 16);
}
__device__ __forceinline__ float bf2f(unsigned short b) {
    return __uint_as_float(((unsigned)b) << 16);
}

// ---- fused: x0 = mean(x,-1) + split x to (hi,lo) bf16 + adjacency buckets ----
__global__ __launch_bounds__(256) void k_combo(
    const float* __restrict__ x, const int* __restrict__ ei,
    unsigned short* __restrict__ hi, unsigned short* __restrict__ lo,
    float* __restrict__ out, unsigned* __restrict__ cnt, int* __restrict__ slots)
{
    int bid = blockIdx.x, t = threadIdx.x;

    // part 1: x0 + split (8 nodes/block, 32 threads/node, float4 each)
    {
        int node = bid * 8 + (t >> 5);
        int q = t & 31;
        float4 v = reinterpret_cast<const float4*>(x)[node * 32 + q];
        ushort4 h, l;
        h.x = f2bf(v.x); l.x = f2bf(v.x - bf2f(h.x));
        h.y = f2bf(v.y); l.y = f2bf(v.y - bf2f(h.y));
        h.z = f2bf(v.z); l.z = f2bf(v.z - bf2f(h.z));
        h.w = f2bf(v.w); l.w = f2bf(v.w - bf2f(h.w));
        reinterpret_cast<ushort4*>(hi)[node * 32 + q] = h;
        reinterpret_cast<ushort4*>(lo)[node * 32 + q] = l;
        float s = v.x + v.y + v.z + v.w;
        #pragma unroll
        for (int o = 16; o; o >>= 1) s += __shfl_xor(s, o);
        if (q == 0) {
            int b = node >> 12;
            int n = node & (N - 1);
            out[b * (3 * N) + n] = s * (1.0f / 128.0f);
        }
    }

    // part 2: adjacency bucket build (first ETOT/256 blocks)
    if (bid < ETOT / 256) {
        int e = bid * 256 + t;
        int s, d;
        if (e < E) { s = ei[e]; d = ei[E + e]; } else { s = d = e - E; }
        unsigned p = atomicAdd(cnt + d, 1u);
        slots[d * CAP + p] = s;
    }
}

// ---- pad buckets to multiple of 4 (+4 prefetch overrun) with sentinel NT;
//      install sentinel rows: asrc[NT] = -1e30 (=> ev = 0), xp[NT] = 0 ----
__global__ __launch_bounds__(256) void k_pad(const unsigned* __restrict__ cnt,
                                             int* __restrict__ slots,
                                             float* __restrict__ asrc,
                                             unsigned short* __restrict__ xpb) {
    int node = blockIdx.x * 256 + threadIdx.x;
    int deg = (int)cnt[node];
    int dp = ((deg + 3) & ~3) + 4;
    int* sl = slots + (size_t)node * CAP;
    for (int i = deg; i < dp; ++i) sl[i] = NT;
    if (node < 4)  asrc[NT * H + node] = -1e30f;
    if (node < 64) reinterpret_cast<uint2*>(xpb)[(size_t)NT * 64 + node] = make_uint2(0u, 0u);
}

// ---- pack Bext = [W | Ws | Wd | 0] (K x 288) into MFMA fragment order ----
__global__ __launch_bounds__(256) void k_pack(
    const float* __restrict__ W, const float* __restrict__ as_,
    const float* __restrict__ ad_,
    unsigned short* __restrict__ Bhi, unsigned short* __restrict__ Blo, int K)
{
    int g = blockIdx.x * 256 + threadIdx.x;   // (K/32)*18*64 threads exactly
    int kt = g / (NTILES * 64);
    int rem = g % (NTILES * 64);
    int nt = rem >> 6, l = rem & 63;
    int n = nt * 16 + (l & 15);
    int bk = kt * 32 + 8 * (l >> 4);
    bf16x8 h, lo;
    #pragma unroll
    for (int j = 0; j < 8; ++j) {
        int k = bk + j;
        float v;
        if (n < 256) {
            v = W[k * D1 + n];
        } else if (n < 264) {
            int idx = n - 256, hh = idx & 3;
            const float* av = (idx < 4) ? as_ : ad_;
            float s = 0.f;
            #pragma unroll 8
            for (int c = 0; c < C; ++c) s += W[k * D1 + hh * C + c] * av[hh * C + c];
            v = s;
        } else {
            v = 0.f;
        }
        unsigned short hb = f2bf(v);
        h[j]  = (short)hb;
        lo[j] = (short)f2bf(v - bf2f(hb));
    }
    size_t slot = ((size_t)(kt * NTILES + nt) * 64 + l) * 8;
    *reinterpret_cast<bf16x8*>(Bhi + slot) = h;
    *reinterpret_cast<bf16x8*>(Blo + slot) = lo;
}

// ---- MFMA GEMM: C[NT x 288] = A[NT x K] * Bext, 3-product bf16 split.
//      BM=32, 4 waves = 2 m-tiles x 2 n-halves; 1 m-tile x 9 nt per wave. ----
template <int K>
__global__ __launch_bounds__(256) void k_mfma(
    const unsigned short* __restrict__ Ahi, const unsigned short* __restrict__ Alo,
    const unsigned short* __restrict__ Bhi, const unsigned short* __restrict__ Blo,
    unsigned short* __restrict__ xpb, float* __restrict__ asrc, float* __restrict__ adst)
{
    int t = threadIdx.x, lane = t & 63, w = t >> 6;
    int wm = w & 1, wn = w >> 1;
    int m0 = blockIdx.x * 32 + wm * 16;
    int ntBase = wn * 9;

    f32x4 acc[9];
    #pragma unroll
    for (int j = 0; j < 9; ++j) acc[j] = (f32x4){0.f, 0.f, 0.f, 0.f};

    int aRow = m0 + (lane & 15);
    int aCol = 8 * (lane >> 4);
    const unsigned short* ah_p = Ahi + (size_t)aRow * K + aCol;
    const unsigned short* al_p = Alo + (size_t)aRow * K + aCol;

    for (int kt = 0; kt < K / 32; ++kt) {
        bf16x8 ah = *reinterpret_cast<const bf16x8*>(ah_p + kt * 32);
        bf16x8 al = *reinterpret_cast<const bf16x8*>(al_p + kt * 32);
        size_t bOff = ((size_t)(kt * NTILES + ntBase) * 64 + lane) * 8;
        const unsigned short* bh = Bhi + bOff;
        const unsigned short* bl = Blo + bOff;
        #pragma unroll
        for (int nt = 0; nt < 9; ++nt) {
            bf16x8 bhv = *reinterpret_cast<const bf16x8*>(bh + nt * 64 * 8);
            bf16x8 blv = *reinterpret_cast<const bf16x8*>(bl + nt * 64 * 8);
            acc[nt] = __builtin_amdgcn_mfma_f32_16x16x32_bf16(ah, bhv, acc[nt], 0, 0, 0);
            acc[nt] = __builtin_amdgcn_mfma_f32_16x16x32_bf16(al, bhv, acc[nt], 0, 0, 0);
            acc[nt] = __builtin_amdgcn_mfma_f32_16x16x32_bf16(ah, blv, acc[nt], 0, 0, 0);
        }
    }

    // epilogue: C layout col = lane&15, row = (lane>>4)*4 + r  [m89-verified]
    int rowB = m0 + (lane >> 4) * 4;
    #pragma unroll
    for (int nt = 0; nt < 9; ++nt) {
        int col = (ntBase + nt) * 16 + (lane & 15);
        #pragma unroll
        for (int r = 0; r < 4; ++r) {
            int row = rowB + r;
            float v = acc[nt][r];
            if (col < 256)      xpb[(size_t)row * D1 + col] = f2bf(v);
            else if (col < 260) asrc[row * H + (col - 256)] = v;
            else if (col < 264) adst[row * H + (col - 260)] = v;
        }
    }
}

// ---- node aggregation: one wave per node, padded buckets (no guards/clamps),
//      4-deep prefetch, unnormalized exp, dword bf16 unpack ----
__global__ __launch_bounds__(256) void k_node(
    const unsigned* __restrict__ cnt, const int* __restrict__ slots,
    const float* __restrict__ asrc, const float* __restrict__ adst,
    const unsigned short* __restrict__ xp,   // bf16 [NT+1][256]
    const float* __restrict__ bias, const float* __restrict__ pw,
    const float* __restrict__ pb,
    unsigned short* __restrict__ hhi, unsigned short* __restrict__ hlo,
    float* __restrict__ out, int sec)
{
    int bid = blockIdx.x;
    int w = threadIdx.x >> 6, lane = threadIdx.x & 63, head = lane >> 4;
    // graph g = bid&7 pinned to XCD g; 4 nodes per block (one per wave)
    int node = ((bid & 7) << 12) | (((bid >> 3) << 2) + w);

    int deg = (int)cnt[node];                 // >= 1 (self loop)
    int dp  = (deg + 3) & ~3;                 // padded length (sentinels -> ev=0)
    const int* sl = slots + (size_t)node * CAP;
    float adh = adst[node * H + head];
    const uint2* xp2 = (const uint2*)xp;      // 4 bf16 per lane as 2 dwords

    float den0 = 0.f, den1 = 0.f;
    float4 acc0 = make_float4(0.f, 0.f, 0.f, 0.f);
    float4 acc1 = make_float4(0.f, 0.f, 0.f, 0.f);

    int   s0 = sl[0], s1 = sl[1], s2 = sl[2], s3 = sl[3];
    float a0 = asrc[s0 * H + head], a1 = asrc[s1 * H + head],
          a2 = asrc[s2 * H + head], a3 = asrc[s3 * H + head];
    uint2 v0 = xp2[s0 * 64 + lane], v1 = xp2[s1 * 64 + lane],
          v2 = xp2[s2 * 64 + lane], v3 = xp2[s3 * 64 + lane];

    for (int i = 0; i < dp; i += 4) {
        int   t0 = sl[i + 4], t1 = sl[i + 5], t2 = sl[i + 6], t3 = sl[i + 7];
        float b0 = asrc[t0 * H + head], b1 = asrc[t1 * H + head],
              b2 = asrc[t2 * H + head], b3 = asrc[t3 * H + head];
        uint2 w0 = xp2[t0 * 64 + lane], w1 = xp2[t1 * 64 + lane],
              w2 = xp2[t2 * 64 + lane], w3 = xp2[t3 * 64 + lane];

        #define PROC(aa, vv, dd, cc)                                        \
        {                                                                   \
            float l  = aa + adh;                                            \
            float ev = __expf(fmaxf(l, 0.2f * l));                          \
            dd += ev;                                                       \
            cc.x = fmaf(ev, __uint_as_float(vv.x << 16),          cc.x);    \
            cc.y = fmaf(ev, __uint_as_float(vv.x & 0xFFFF0000u),  cc.y);    \
            cc.z = fmaf(ev, __uint_as_float(vv.y << 16),          cc.z);    \
            cc.w = fmaf(ev, __uint_as_float(vv.y & 0xFFFF0000u),  cc.w);    \
        }
        PROC(a0, v0, den0, acc0)
        PROC(a1, v1, den1, acc1)
        PROC(a2, v2, den0, acc0)
        PROC(a3, v3, den1, acc1)
        #undef PROC
        s0 = t0; s1 = t1; s2 = t2; s3 = t3;
        a0 = b0; a1 = b1; a2 = b2; a3 = b3;
        v0 = w0; v1 = w1; v2 = w2; v3 = w3;
    }

    // per-lane finish (den identical within each 16-lane head group)
    float den = den0 + den1;
    float4 bias4 = reinterpret_cast<const float4*>(bias)[lane];
    float4 pw4   = reinterpret_cast<const float4*>(pw)[lane];
    float invd = 1.f / (den + 1e-16f);
    float4 hv;
    hv.x = fmaf(acc0.x + acc1.x, invd, bias4.x);
    hv.y = fmaf(acc0.y + acc1.y, invd, bias4.y);
    hv.z = fmaf(acc0.z + acc1.z, invd, bias4.z);
    hv.w = fmaf(acc0.w + acc1.w, invd, bias4.w);
    hv.x = hv.x > 0.f ? hv.x : __expf(hv.x) - 1.f;
    hv.y = hv.y > 0.f ? hv.y : __expf(hv.y) - 1.f;
    hv.z = hv.z > 0.f ? hv.z : __expf(hv.z) - 1.f;
    hv.w = hv.w > 0.f ? hv.w : __expf(hv.w) - 1.f;

    if (hhi) {
        ushort4 hh, hl;
        hh.x = f2bf(hv.x); hl.x = f2bf(hv.x - bf2f(hh.x));
        hh.y = f2bf(hv.y); hl.y = f2bf(hv.y - bf2f(hh.y));
        hh.z = f2bf(hv.z); hl.z = f2bf(hv.z - bf2f(hh.z));
        hh.w = f2bf(hv.w); hl.w = f2bf(hv.w - bf2f(hh.w));
        reinterpret_cast<ushort4*>(hhi)[node * 64 + lane] = hh;
        reinterpret_cast<ushort4*>(hlo)[node * 64 + lane] = hl;
    }

    float p = hv.x * pw4.x + hv.y * pw4.y + hv.z * pw4.z + hv.w * pw4.w;
    #pragma unroll
    for (int o = 32; o; o >>= 1) p += __shfl_xor(p, o);
    if (lane == 0) {
        int b = node >> 12;
        int n = node & (N - 1);
        out[b * (3 * N) + sec * N + n] = p + pb[0];
    }
}

extern "C" void kernel_launch(void* const* d_in, const int* in_sizes, int n_in,
                              void* d_out, int out_size, void* d_ws, size_t ws_size,
                              hipStream_t stream) {
    const float* x   = (const float*)d_in[0];
    const int*   ei  = (const int*)d_in[1];
    const float* W1  = (const float*)d_in[2];
    const float* as1 = (const float*)d_in[3];
    const float* ad1 = (const float*)d_in[4];
    const float* b1  = (const float*)d_in[5];
    const float* W2  = (const float*)d_in[6];
    const float* as2 = (const float*)d_in[7];
    const float* ad2 = (const float*)d_in[8];
    const float* b2  = (const float*)d_in[9];
    const float* pw1 = (const float*)d_in[10];
    const float* pb1 = (const float*)d_in[11];
    const float* pw2 = (const float*)d_in[12];
    const float* pb2 = (const float*)d_in[13];
    float* out = (float*)d_out;

    // workspace layout (16B aligned blocks); xpb/asrc have +1 sentinel row
    unsigned short* xpb  = (unsigned short*)d_ws;             // (NT+1)*D1 bf16
    unsigned short* xhi  = xpb  + (size_t)(NT + 1) * D1;      // NT*FIN
    unsigned short* xlo  = xhi  + (size_t)NT * FIN;           // NT*FIN
    unsigned short* h1hi = xlo  + (size_t)NT * FIN;           // NT*D1
    unsigned short* h1lo = h1hi + (size_t)NT * D1;            // NT*D1
    float*    asrc   = (float*)(h1lo + (size_t)NT * D1);      // (NT+1)*H
    float*    adst   = asrc + (size_t)(NT + 1) * H;           // NT*H
    unsigned short* pB1hi = (unsigned short*)(adst + (size_t)NT * H); // 4*18*64*8
    unsigned short* pB1lo = pB1hi + (size_t)4 * NTILES * 64 * 8;
    unsigned short* pB2hi = pB1lo + (size_t)4 * NTILES * 64 * 8;      // 8*18*64*8
    unsigned short* pB2lo = pB2hi + (size_t)8 * NTILES * 64 * 8;
    unsigned* cnt    = (unsigned*)(pB2lo + (size_t)8 * NTILES * 64 * 8); // NT
    int*      slots  = (int*)(cnt + NT);                      // NT*CAP

    hipMemsetAsync(cnt, 0, (size_t)NT * sizeof(unsigned), stream);
    k_combo<<<NT / 8, 256, 0, stream>>>(x, ei, xhi, xlo, out, cnt, slots);
    k_pad<<<NT / 256, 256, 0, stream>>>(cnt, slots, asrc, xpb);
    k_pack<<<(128 / 32) * NTILES * 64 / 256, 256, 0, stream>>>(W1, as1, ad1, pB1hi, pB1lo, 128);
    k_pack<<<(256 / 32) * NTILES * 64 / 256, 256, 0, stream>>>(W2, as2, ad2, pB2hi, pB2lo, 256);

    // ---------------- layer 1 (K = 128) ----------------
    k_mfma<128><<<NT / 32, 256, 0, stream>>>(xhi, xlo, pB1hi, pB1lo, xpb, asrc, adst);
    k_node<<<NT / 4, 256, 0, stream>>>(cnt, slots, asrc, adst, xpb,
                                       b1, pw1, pb1, h1hi, h1lo, out, 1);

    // ---------------- layer 2 (K = 256) ----------------
    k_mfma<256><<<NT / 32, 256, 0, stream>>>(h1hi, h1lo, pB2hi, pB2lo, xpb, asrc, adst);
    k_node<<<NT / 4, 256, 0, stream>>>(cnt, slots, asrc, adst, xpb,
                                       b2, pw2, pb2, nullptr, nullptr, out, 2);
}

// Round 9
// 163.082 us; speedup vs baseline: 1.2260x; 1.2260x over previous
//
#include <hip/hip_runtime.h>

typedef __attribute__((ext_vector_type(8))) short bf16x8;
typedef __attribute__((ext_vector_type(4))) float f32x4;

// Problem constants (from reference)
constexpr int B    = 8;
constexpr int N    = 4096;
constexpr int FIN  = 128;
constexpr int NT   = B * N;        // 32768
constexpr int H    = 4;
constexpr int C    = 64;
constexpr int D1   = H * C;        // 256
constexpr int E    = 524288;
constexpr int ETOT = E + NT;       // 557056
constexpr int NSLOT = 18;          // per-kt B slots: 0..16 = bh(nt0..16), 17 = blAtt(nt16)
constexpr int CAP  = 64;           // adjacency bucket capacity (max deg ~40, pad <= 48)

// bf16 round-to-nearest-even helpers
__device__ __forceinline__ unsigned short f2bf(float f) {
    unsigned u = __float_as_uint(f);
    return (unsigned short)((u + 0x7FFFu + ((u >> 16) & 1u)) >> 16);
}
__device__ __forceinline__ float bf2f(unsigned short b) {
    return __uint_as_float(((unsigned)b) << 16);
}

// ---- pack one layer's Bext = [W | Ws | Wd | 0] into per-kt slot layout ----
// slot<17: hi(Bext[k][slot*16 + l15]); slot==17: lo(Bext[k][256 + l15]) (att cols)
__device__ __forceinline__ void pack_body(
    const float* __restrict__ W, const float* __restrict__ as_,
    const float* __restrict__ ad_, unsigned short* __restrict__ pB, int g)
{
    int kt  = g / (NSLOT * 64);
    int rem = g % (NSLOT * 64);
    int slot = rem >> 6, l = rem & 63;
    int k0 = kt * 32 + 8 * (l >> 4);
    bool wantLo = (slot == 17);
    int nt = wantLo ? 16 : slot;
    int n  = nt * 16 + (l & 15);
    bf16x8 o;
    #pragma unroll
    for (int j = 0; j < 8; ++j) {
        int k = k0 + j;
        float v;
        if (n < 256) {
            v = W[k * D1 + n];
        } else if (n < 264) {
            int idx = n - 256, hh = idx & 3;
            const float* av = (idx < 4) ? as_ : ad_;
            float s = 0.f;
            #pragma unroll 8
            for (int c = 0; c < C; ++c) s += W[k * D1 + hh * C + c] * av[hh * C + c];
            v = s;
        } else {
            v = 0.f;
        }
        unsigned short hb = f2bf(v);
        o[j] = wantLo ? (short)f2bf(v - bf2f(hb)) : (short)hb;
    }
    *reinterpret_cast<bf16x8*>(pB + (size_t)g * 8) = o;
}

// ---- fused prep: pack B1 (18 blk) + pack B2 (36 blk) + zero cnt (128 blk) ----
__global__ __launch_bounds__(256) void k_prep(
    const float* __restrict__ W1, const float* __restrict__ as1, const float* __restrict__ ad1,
    const float* __restrict__ W2, const float* __restrict__ as2, const float* __restrict__ ad2,
    unsigned short* __restrict__ pB1, unsigned short* __restrict__ pB2,
    unsigned* __restrict__ cnt)
{
    int bid = blockIdx.x, t = threadIdx.x;
    if (bid < 18)       pack_body(W1, as1, ad1, pB1, bid * 256 + t);
    else if (bid < 54)  pack_body(W2, as2, ad2, pB2, (bid - 18) * 256 + t);
    else                cnt[(bid - 54) * 256 + t] = 0u;
}

// ---- fused: x0 = mean(x,-1) + split x to (hi,lo) bf16 + adjacency buckets ----
__global__ __launch_bounds__(256) void k_combo(
    const float* __restrict__ x, const int* __restrict__ ei,
    unsigned short* __restrict__ hi, unsigned short* __restrict__ lo,
    float* __restrict__ out, unsigned* __restrict__ cnt, int* __restrict__ slots)
{
    int bid = blockIdx.x, t = threadIdx.x;

    // part 1: x0 + split (8 nodes/block, 32 threads/node, float4 each)
    {
        int node = bid * 8 + (t >> 5);
        int q = t & 31;
        float4 v = reinterpret_cast<const float4*>(x)[node * 32 + q];
        ushort4 h, l;
        h.x = f2bf(v.x); l.x = f2bf(v.x - bf2f(h.x));
        h.y = f2bf(v.y); l.y = f2bf(v.y - bf2f(h.y));
        h.z = f2bf(v.z); l.z = f2bf(v.z - bf2f(h.z));
        h.w = f2bf(v.w); l.w = f2bf(v.w - bf2f(h.w));
        reinterpret_cast<ushort4*>(hi)[node * 32 + q] = h;
        reinterpret_cast<ushort4*>(lo)[node * 32 + q] = l;
        float s = v.x + v.y + v.z + v.w;
        #pragma unroll
        for (int o = 16; o; o >>= 1) s += __shfl_xor(s, o);
        if (q == 0) {
            int b = node >> 12;
            int n = node & (N - 1);
            out[b * (3 * N) + n] = s * (1.0f / 128.0f);
        }
    }

    // part 2: adjacency bucket build, slots hold PRE-SCALED src*H
    if (bid < ETOT / 256) {
        int e = bid * 256 + t;
        int s, d;
        if (e < E) { s = ei[e]; d = ei[E + e]; } else { s = d = e - E; }
        unsigned p = atomicAdd(cnt + d, 1u);
        slots[d * CAP + p] = s * 4;
    }
}

// ---- pad buckets to multiple of 4 (+4 overrun) with sentinel NT*4;
//      sentinel rows: asrc[NT] = -1e30 (=> ev = 0), xp[NT] = 0 ----
__global__ __launch_bounds__(256) void k_pad(const unsigned* __restrict__ cnt,
                                             int* __restrict__ slots,
                                             float* __restrict__ asrc,
                                             unsigned short* __restrict__ xpb) {
    int node = blockIdx.x * 256 + threadIdx.x;
    int deg = (int)cnt[node];
    int dp = ((deg + 3) & ~3) + 4;
    int* sl = slots + (size_t)node * CAP;
    for (int i = deg; i < dp; ++i) sl[i] = NT * 4;
    if (node < 4)  asrc[NT * H + node] = -1e30f;
    if (node < 64) reinterpret_cast<uint2*>(xpb)[(size_t)NT * 64 + node] = make_uint2(0u, 0u);
}

// ---- MFMA GEMM: C[NT x 264] = A[NT x K] * Bext, software-pipelined.
//      BM=64; 4 waves = 2 wm x 2 wn; wave: 2 m-tiles x 9 slots.
//      xp cols: 2-product (ah*bh + al*bh); att cols: +ah*blAtt (3-product). ----
template <int K>
__global__ __launch_bounds__(256) void k_mfma(
    const unsigned short* __restrict__ Ahi, const unsigned short* __restrict__ Alo,
    const unsigned short* __restrict__ pB,
    unsigned short* __restrict__ xpb, float* __restrict__ asrc, float* __restrict__ adst)
{
    constexpr int KT = K / 32;
    int t = threadIdx.x, lane = t & 63, w = t >> 6;
    int wm = w & 1, wn = w >> 1;
    int m0 = blockIdx.x * 64 + wm * 32;
    int sBase = wn * 9;

    f32x4 acc[2][9];
    #pragma unroll
    for (int i = 0; i < 2; ++i)
        #pragma unroll
        for (int j = 0; j < 9; ++j)
            acc[i][j] = (f32x4){0.f, 0.f, 0.f, 0.f};

    int aRow = m0 + (lane & 15);
    int aCol = 8 * (lane >> 4);
    const unsigned short* a0h = Ahi + (size_t)aRow * K + aCol;
    const unsigned short* a0l = Alo + (size_t)aRow * K + aCol;
    const unsigned short* bp  = pB + ((size_t)sBase * 64 + lane) * 8;

    bf16x8 bc[9], bn[9];
    bf16x8 ah0c, al0c, ah1c, al1c, ah0n, al0n, ah1n, al1n;

    // prologue: kt = 0 fragments
    #pragma unroll
    for (int j = 0; j < 9; ++j) bc[j] = *reinterpret_cast<const bf16x8*>(bp + j * 512);
    ah0c = *reinterpret_cast<const bf16x8*>(a0h);
    al0c = *reinterpret_cast<const bf16x8*>(a0l);
    ah1c = *reinterpret_cast<const bf16x8*>(a0h + 16 * K);
    al1c = *reinterpret_cast<const bf16x8*>(a0l + 16 * K);

    #pragma unroll
    for (int kt = 0; kt < KT; ++kt) {
        if (kt + 1 < KT) {
            const unsigned short* bpn = bp + (size_t)(kt + 1) * NSLOT * 64 * 8;
            #pragma unroll
            for (int j = 0; j < 9; ++j) bn[j] = *reinterpret_cast<const bf16x8*>(bpn + j * 512);
            ah0n = *reinterpret_cast<const bf16x8*>(a0h + (kt + 1) * 32);
            al0n = *reinterpret_cast<const bf16x8*>(a0l + (kt + 1) * 32);
            ah1n = *reinterpret_cast<const bf16x8*>(a0h + 16 * K + (kt + 1) * 32);
            al1n = *reinterpret_cast<const bf16x8*>(a0l + 16 * K + (kt + 1) * 32);
        }
        __builtin_amdgcn_sched_barrier(0);   // keep prefetch loads ahead of MFMAs
        if (wn == 0) {
            #pragma unroll
            for (int j = 0; j < 9; ++j) {
                acc[0][j] = __builtin_amdgcn_mfma_f32_16x16x32_bf16(ah0c, bc[j], acc[0][j], 0, 0, 0);
                acc[1][j] = __builtin_amdgcn_mfma_f32_16x16x32_bf16(ah1c, bc[j], acc[1][j], 0, 0, 0);
                acc[0][j] = __builtin_amdgcn_mfma_f32_16x16x32_bf16(al0c, bc[j], acc[0][j], 0, 0, 0);
                acc[1][j] = __builtin_amdgcn_mfma_f32_16x16x32_bf16(al1c, bc[j], acc[1][j], 0, 0, 0);
            }
        } else {
            #pragma unroll
            for (int j = 0; j < 8; ++j) {
                acc[0][j] = __builtin_amdgcn_mfma_f32_16x16x32_bf16(ah0c, bc[j], acc[0][j], 0, 0, 0);
                acc[1][j] = __builtin_amdgcn_mfma_f32_16x16x32_bf16(ah1c, bc[j], acc[1][j], 0, 0, 0);
                acc[0][j] = __builtin_amdgcn_mfma_f32_16x16x32_bf16(al0c, bc[j], acc[0][j], 0, 0, 0);
                acc[1][j] = __builtin_amdgcn_mfma_f32_16x16x32_bf16(al1c, bc[j], acc[1][j], 0, 0, 0);
            }
            // att-lo product into the nt16 accumulator (j = 7)
            acc[0][7] = __builtin_amdgcn_mfma_f32_16x16x32_bf16(ah0c, bc[8], acc[0][7], 0, 0, 0);
            acc[1][7] = __builtin_amdgcn_mfma_f32_16x16x32_bf16(ah1c, bc[8], acc[1][7], 0, 0, 0);
        }
        if (kt + 1 < KT) {   // rotation (renamed away by full unroll)
            #pragma unroll
            for (int j = 0; j < 9; ++j) bc[j] = bn[j];
            ah0c = ah0n; al0c = al0n; ah1c = ah1n; al1c = al1n;
        }
    }

    // epilogue: C layout col = lane&15, row = (lane>>4)*4 + r  [m89-verified]
    #pragma unroll
    for (int mt = 0; mt < 2; ++mt) {
        int rowB = m0 + mt * 16 + (lane >> 4) * 4;
        if (wn == 0) {
            #pragma unroll
            for (int j = 0; j < 9; ++j) {
                int col = j * 16 + (lane & 15);
                #pragma unroll
                for (int r = 0; r < 4; ++r)
                    xpb[(size_t)(rowB + r) * D1 + col] = f2bf(acc[mt][j][r]);
            }
        } else {
            #pragma unroll
            for (int j = 0; j < 8; ++j) {
                int nt = 9 + j;
                int col = nt * 16 + (lane & 15);
                #pragma unroll
                for (int r = 0; r < 4; ++r) {
                    int row = rowB + r;
                    float v = acc[mt][j][r];
                    if (col < 256)      xpb[(size_t)row * D1 + col] = f2bf(v);
                    else if (col < 260) asrc[row * H + (col - 256)] = v;
                    else if (col < 264) adst[row * H + (col - 260)] = v;
                }
            }
        }
    }
}

// ---- node aggregation: one wave per node, padded buckets, pre-scaled slots,
//      4-deep prefetch, unnormalized exp, dword bf16 unpack ----
__global__ __launch_bounds__(256) void k_node(
    const unsigned* __restrict__ cnt, const int* __restrict__ slots,
    const float* __restrict__ asrc, const float* __restrict__ adst,
    const unsigned short* __restrict__ xp,   // bf16 [NT+1][256]
    const float* __restrict__ bias, const float* __restrict__ pw,
    const float* __restrict__ pb,
    unsigned short* __restrict__ hhi, unsigned short* __restrict__ hlo,
    float* __restrict__ out, int sec)
{
    int bid = blockIdx.x;
    int w = threadIdx.x >> 6, lane = threadIdx.x & 63, head = lane >> 4;
    // graph g = bid&7 pinned to XCD g; 4 nodes per block (one per wave)
    int node = ((bid & 7) << 12) | (((bid >> 3) << 2) + w);

    int deg = (int)cnt[node];                 // >= 1 (self loop)
    int dp  = (deg + 3) & ~3;
    const int* sl = slots + (size_t)node * CAP;
    float adh = adst[node * H + head];
    const uint2* xp2 = (const uint2*)xp;

    float den0 = 0.f, den1 = 0.f;
    float4 acc0 = make_float4(0.f, 0.f, 0.f, 0.f);
    float4 acc1 = make_float4(0.f, 0.f, 0.f, 0.f);

    int   s0 = sl[0], s1 = sl[1], s2 = sl[2], s3 = sl[3];   // pre-scaled s*4
    float a0 = asrc[s0 + head], a1 = asrc[s1 + head],
          a2 = asrc[s2 + head], a3 = asrc[s3 + head];
    uint2 v0 = xp2[(s0 << 4) + lane], v1 = xp2[(s1 << 4) + lane],
          v2 = xp2[(s2 << 4) + lane], v3 = xp2[(s3 << 4) + lane];

    #pragma unroll 2
    for (int i = 0; i < dp; i += 4) {
        int   t0 = sl[i + 4], t1 = sl[i + 5], t2 = sl[i + 6], t3 = sl[i + 7];
        float b0 = asrc[t0 + head], b1 = asrc[t1 + head],
              b2 = asrc[t2 + head], b3 = asrc[t3 + head];
        uint2 w0 = xp2[(t0 << 4) + lane], w1 = xp2[(t1 << 4) + lane],
              w2 = xp2[(t2 << 4) + lane], w3 = xp2[(t3 << 4) + lane];

        #define PROC(aa, vv, dd, cc)                                        \
        {                                                                   \
            float l  = aa + adh;                                            \
            float ev = __expf(fmaxf(l, 0.2f * l));                          \
            dd += ev;                                                       \
            cc.x = fmaf(ev, __uint_as_float(vv.x << 16),          cc.x);    \
            cc.y = fmaf(ev, __uint_as_float(vv.x & 0xFFFF0000u),  cc.y);    \
            cc.z = fmaf(ev, __uint_as_float(vv.y << 16),          cc.z);    \
            cc.w = fmaf(ev, __uint_as_float(vv.y & 0xFFFF0000u),  cc.w);    \
        }
        PROC(a0, v0, den0, acc0)
        PROC(a1, v1, den1, acc1)
        PROC(a2, v2, den0, acc0)
        PROC(a3, v3, den1, acc1)
        #undef PROC
        s0 = t0; s1 = t1; s2 = t2; s3 = t3;
        a0 = b0; a1 = b1; a2 = b2; a3 = b3;
        v0 = w0; v1 = w1; v2 = w2; v3 = w3;
    }

    // per-lane finish (den identical within each 16-lane head group)
    float den = den0 + den1;
    float4 bias4 = reinterpret_cast<const float4*>(bias)[lane];
    float4 pw4   = reinterpret_cast<const float4*>(pw)[lane];
    float invd = 1.f / (den + 1e-16f);
    float4 hv;
    hv.x = fmaf(acc0.x + acc1.x, invd, bias4.x);
    hv.y = fmaf(acc0.y + acc1.y, invd, bias4.y);
    hv.z = fmaf(acc0.z + acc1.z, invd, bias4.z);
    hv.w = fmaf(acc0.w + acc1.w, invd, bias4.w);
    hv.x = hv.x > 0.f ? hv.x : __expf(hv.x) - 1.f;
    hv.y = hv.y > 0.f ? hv.y : __expf(hv.y) - 1.f;
    hv.z = hv.z > 0.f ? hv.z : __expf(hv.z) - 1.f;
    hv.w = hv.w > 0.f ? hv.w : __expf(hv.w) - 1.f;

    if (hhi) {
        ushort4 hh, hl;
        hh.x = f2bf(hv.x); hl.x = f2bf(hv.x - bf2f(hh.x));
        hh.y = f2bf(hv.y); hl.y = f2bf(hv.y - bf2f(hh.y));
        hh.z = f2bf(hv.z); hl.z = f2bf(hv.z - bf2f(hh.z));
        hh.w = f2bf(hv.w); hl.w = f2bf(hv.w - bf2f(hh.w));
        reinterpret_cast<ushort4*>(hhi)[node * 64 + lane] = hh;
        reinterpret_cast<ushort4*>(hlo)[node * 64 + lane] = hl;
    }

    float p = hv.x * pw4.x + hv.y * pw4.y + hv.z * pw4.z + hv.w * pw4.w;
    #pragma unroll
    for (int o = 32; o; o >>= 1) p += __shfl_xor(p, o);
    if (lane == 0) {
        int b = node >> 12;
        int n = node & (N - 1);
        out[b * (3 * N) + sec * N + n] = p + pb[0];
    }
}

extern "C" void kernel_launch(void* const* d_in, const int* in_sizes, int n_in,
                              void* d_out, int out_size, void* d_ws, size_t ws_size,
                              hipStream_t stream) {
    const float* x   = (const float*)d_in[0];
    const int*   ei  = (const int*)d_in[1];
    const float* W1  = (const float*)d_in[2];
    const float* as1 = (const float*)d_in[3];
    const float* ad1 = (const float*)d_in[4];
    const float* b1  = (const float*)d_in[5];
    const float* W2  = (const float*)d_in[6];
    const float* as2 = (const float*)d_in[7];
    const float* ad2 = (const float*)d_in[8];
    const float* b2  = (const float*)d_in[9];
    const float* pw1 = (const float*)d_in[10];
    const float* pb1 = (const float*)d_in[11];
    const float* pw2 = (const float*)d_in[12];
    const float* pb2 = (const float*)d_in[13];
    float* out = (float*)d_out;

    // workspace layout (16B aligned blocks); xpb/asrc have +1 sentinel row
    unsigned short* xpb  = (unsigned short*)d_ws;             // (NT+1)*D1 bf16
    unsigned short* xhi  = xpb  + (size_t)(NT + 1) * D1;      // NT*FIN
    unsigned short* xlo  = xhi  + (size_t)NT * FIN;           // NT*FIN
    unsigned short* h1hi = xlo  + (size_t)NT * FIN;           // NT*D1
    unsigned short* h1lo = h1hi + (size_t)NT * D1;            // NT*D1
    float*    asrc   = (float*)(h1lo + (size_t)NT * D1);      // (NT+1)*H
    float*    adst   = asrc + (size_t)(NT + 1) * H;           // NT*H
    unsigned short* pB1 = (unsigned short*)(adst + (size_t)NT * H); // 4*18*64*8
    unsigned short* pB2 = pB1 + (size_t)4 * NSLOT * 64 * 8;         // 8*18*64*8
    unsigned* cnt    = (unsigned*)(pB2 + (size_t)8 * NSLOT * 64 * 8); // NT
    int*      slots  = (int*)(cnt + NT);                      // NT*CAP

    // 7 dispatches total, no hipMemset
    k_prep<<<182, 256, 0, stream>>>(W1, as1, ad1, W2, as2, ad2, pB1, pB2, cnt);
    k_combo<<<NT / 8, 256, 0, stream>>>(x, ei, xhi, xlo, out, cnt, slots);
    k_pad<<<NT / 256, 256, 0, stream>>>(cnt, slots, asrc, xpb);

    // ---------------- layer 1 (K = 128) ----------------
    k_mfma<128><<<NT / 64, 256, 0, stream>>>(xhi, xlo, pB1, xpb, asrc, adst);
    k_node<<<NT / 4, 256, 0, stream>>>(cnt, slots, asrc, adst, xpb,
                                       b1, pw1, pb1, h1hi, h1lo, out, 1);

    // ---------------- layer 2 (K = 256) ----------------
    k_mfma<256><<<NT / 64, 256, 0, stream>>>(h1hi, h1lo, pB2, xpb, asrc, adst);
    k_node<<<NT / 4, 256, 0, stream>>>(cnt, slots, asrc, adst, xpb,
                                       b2, pw2, pb2, nullptr, nullptr, out, 2);
}

// Round 10
// 150.250 us; speedup vs baseline: 1.3307x; 1.0854x over previous
//
#include <hip/hip_runtime.h>

typedef __attribute__((ext_vector_type(8))) short bf16x8;
typedef __attribute__((ext_vector_type(4))) float f32x4;

// Problem constants (from reference)
constexpr int B    = 8;
constexpr int N    = 4096;
constexpr int FIN  = 128;
constexpr int NT   = B * N;        // 32768
constexpr int H    = 4;
constexpr int C    = 64;
constexpr int D1   = H * C;        // 256
constexpr int E    = 524288;
constexpr int ETOT = E + NT;       // 557056
constexpr int NSLOT = 18;          // per-kt B slots: 0..16 = bh(nt0..16), 17 = blAtt(nt16)
constexpr int CAP  = 64;           // adjacency bucket capacity (max deg ~40, pad <= 48)

// bf16 round-to-nearest-even helpers
__device__ __forceinline__ unsigned short f2bf(float f) {
    unsigned u = __float_as_uint(f);
    return (unsigned short)((u + 0x7FFFu + ((u >> 16) & 1u)) >> 16);
}
__device__ __forceinline__ float bf2f(unsigned short b) {
    return __uint_as_float(((unsigned)b) << 16);
}

// ---- pack one layer's Bext = [W | Ws | Wd | 0] into per-kt slot layout ----
__device__ __forceinline__ void pack_body(
    const float* __restrict__ W, const float* __restrict__ as_,
    const float* __restrict__ ad_, unsigned short* __restrict__ pB, int g)
{
    int kt  = g / (NSLOT * 64);
    int rem = g % (NSLOT * 64);
    int slot = rem >> 6, l = rem & 63;
    int k0 = kt * 32 + 8 * (l >> 4);
    bool wantLo = (slot == 17);
    int nt = wantLo ? 16 : slot;
    int n  = nt * 16 + (l & 15);
    bf16x8 o;
    #pragma unroll
    for (int j = 0; j < 8; ++j) {
        int k = k0 + j;
        float v;
        if (n < 256) {
            v = W[k * D1 + n];
        } else if (n < 264) {
            int idx = n - 256, hh = idx & 3;
            const float* av = (idx < 4) ? as_ : ad_;
            float s = 0.f;
            #pragma unroll 8
            for (int c = 0; c < C; ++c) s += W[k * D1 + hh * C + c] * av[hh * C + c];
            v = s;
        } else {
            v = 0.f;
        }
        unsigned short hb = f2bf(v);
        o[j] = wantLo ? (short)f2bf(v - bf2f(hb)) : (short)hb;
    }
    *reinterpret_cast<bf16x8*>(pB + (size_t)g * 8) = o;
}

// ---- fused prep: pack B1 (18 blk) + pack B2 (36 blk) + zero cnt (128 blk) ----
__global__ __launch_bounds__(256) void k_prep(
    const float* __restrict__ W1, const float* __restrict__ as1, const float* __restrict__ ad1,
    const float* __restrict__ W2, const float* __restrict__ as2, const float* __restrict__ ad2,
    unsigned short* __restrict__ pB1, unsigned short* __restrict__ pB2,
    unsigned* __restrict__ cnt)
{
    int bid = blockIdx.x, t = threadIdx.x;
    if (bid < 18)       pack_body(W1, as1, ad1, pB1, bid * 256 + t);
    else if (bid < 54)  pack_body(W2, as2, ad2, pB2, (bid - 18) * 256 + t);
    else                cnt[(bid - 54) * 256 + t] = 0u;
}

// ---- fused: x0 = mean(x,-1) + split x to (hi,lo) bf16 + adjacency buckets ----
__global__ __launch_bounds__(256) void k_combo(
    const float* __restrict__ x, const int* __restrict__ ei,
    unsigned short* __restrict__ hi, unsigned short* __restrict__ lo,
    float* __restrict__ out, unsigned* __restrict__ cnt, int* __restrict__ slots)
{
    int bid = blockIdx.x, t = threadIdx.x;

    // part 1: x0 + split (8 nodes/block, 32 threads/node, float4 each)
    {
        int node = bid * 8 + (t >> 5);
        int q = t & 31;
        float4 v = reinterpret_cast<const float4*>(x)[node * 32 + q];
        ushort4 h, l;
        h.x = f2bf(v.x); l.x = f2bf(v.x - bf2f(h.x));
        h.y = f2bf(v.y); l.y = f2bf(v.y - bf2f(h.y));
        h.z = f2bf(v.z); l.z = f2bf(v.z - bf2f(h.z));
        h.w = f2bf(v.w); l.w = f2bf(v.w - bf2f(h.w));
        reinterpret_cast<ushort4*>(hi)[node * 32 + q] = h;
        reinterpret_cast<ushort4*>(lo)[node * 32 + q] = l;
        float s = v.x + v.y + v.z + v.w;
        #pragma unroll
        for (int o = 16; o; o >>= 1) s += __shfl_xor(s, o);
        if (q == 0) {
            int b = node >> 12;
            int n = node & (N - 1);
            out[b * (3 * N) + n] = s * (1.0f / 128.0f);
        }
    }

    // part 2: adjacency bucket build, slots hold PRE-SCALED src*H
    if (bid < ETOT / 256) {
        int e = bid * 256 + t;
        int s, d;
        if (e < E) { s = ei[e]; d = ei[E + e]; } else { s = d = e - E; }
        unsigned p = atomicAdd(cnt + d, 1u);
        slots[d * CAP + p] = s * 4;
    }
}

// ---- pad buckets to multiple of 4 (+4 overrun) with sentinel NT*4;
//      sentinel rows: asrc[NT] = -1e30 (=> ev = 0), xp[NT] = 0 ----
__global__ __launch_bounds__(256) void k_pad(const unsigned* __restrict__ cnt,
                                             int* __restrict__ slots,
                                             float* __restrict__ asrc,
                                             unsigned short* __restrict__ xpb) {
    int node = blockIdx.x * 256 + threadIdx.x;
    int deg = (int)cnt[node];
    int dp = ((deg + 3) & ~3) + 4;
    int* sl = slots + (size_t)node * CAP;
    for (int i = deg; i < dp; ++i) sl[i] = NT * 4;
    if (node < 4)  asrc[NT * H + node] = -1e30f;
    if (node < 64) reinterpret_cast<uint2*>(xpb)[(size_t)NT * 64 + node] = make_uint2(0u, 0u);
}

// ---- MFMA GEMM: C[NT x 264] = A[NT x K] * Bext, software-pipelined.
//      BM=64; 4 waves = 2 wm x 2 wn; wave: 2 m-tiles x 9 slots.
//      xp cols: 2-product (ah*bh + al*bh); att cols: +ah*blAtt (3-product). ----
template <int K>
__global__ __launch_bounds__(256) void k_mfma(
    const unsigned short* __restrict__ Ahi, const unsigned short* __restrict__ Alo,
    const unsigned short* __restrict__ pB,
    unsigned short* __restrict__ xpb, float* __restrict__ asrc, float* __restrict__ adst)
{
    constexpr int KT = K / 32;
    int t = threadIdx.x, lane = t & 63, w = t >> 6;
    int wm = w & 1, wn = w >> 1;
    int m0 = blockIdx.x * 64 + wm * 32;
    int sBase = wn * 9;

    f32x4 acc[2][9];
    #pragma unroll
    for (int i = 0; i < 2; ++i)
        #pragma unroll
        for (int j = 0; j < 9; ++j)
            acc[i][j] = (f32x4){0.f, 0.f, 0.f, 0.f};

    int aRow = m0 + (lane & 15);
    int aCol = 8 * (lane >> 4);
    const unsigned short* a0h = Ahi + (size_t)aRow * K + aCol;
    const unsigned short* a0l = Alo + (size_t)aRow * K + aCol;
    const unsigned short* bp  = pB + ((size_t)sBase * 64 + lane) * 8;

    bf16x8 bc[9], bn[9];
    bf16x8 ah0c, al0c, ah1c, al1c, ah0n, al0n, ah1n, al1n;

    #pragma unroll
    for (int j = 0; j < 9; ++j) bc[j] = *reinterpret_cast<const bf16x8*>(bp + j * 512);
    ah0c = *reinterpret_cast<const bf16x8*>(a0h);
    al0c = *reinterpret_cast<const bf16x8*>(a0l);
    ah1c = *reinterpret_cast<const bf16x8*>(a0h + 16 * K);
    al1c = *reinterpret_cast<const bf16x8*>(a0l + 16 * K);

    #pragma unroll
    for (int kt = 0; kt < KT; ++kt) {
        if (kt + 1 < KT) {
            const unsigned short* bpn = bp + (size_t)(kt + 1) * NSLOT * 64 * 8;
            #pragma unroll
            for (int j = 0; j < 9; ++j) bn[j] = *reinterpret_cast<const bf16x8*>(bpn + j * 512);
            ah0n = *reinterpret_cast<const bf16x8*>(a0h + (kt + 1) * 32);
            al0n = *reinterpret_cast<const bf16x8*>(a0l + (kt + 1) * 32);
            ah1n = *reinterpret_cast<const bf16x8*>(a0h + 16 * K + (kt + 1) * 32);
            al1n = *reinterpret_cast<const bf16x8*>(a0l + 16 * K + (kt + 1) * 32);
        }
        __builtin_amdgcn_sched_barrier(0);   // keep prefetch loads ahead of MFMAs
        if (wn == 0) {
            #pragma unroll
            for (int j = 0; j < 9; ++j) {
                acc[0][j] = __builtin_amdgcn_mfma_f32_16x16x32_bf16(ah0c, bc[j], acc[0][j], 0, 0, 0);
                acc[1][j] = __builtin_amdgcn_mfma_f32_16x16x32_bf16(ah1c, bc[j], acc[1][j], 0, 0, 0);
                acc[0][j] = __builtin_amdgcn_mfma_f32_16x16x32_bf16(al0c, bc[j], acc[0][j], 0, 0, 0);
                acc[1][j] = __builtin_amdgcn_mfma_f32_16x16x32_bf16(al1c, bc[j], acc[1][j], 0, 0, 0);
            }
        } else {
            #pragma unroll
            for (int j = 0; j < 8; ++j) {
                acc[0][j] = __builtin_amdgcn_mfma_f32_16x16x32_bf16(ah0c, bc[j], acc[0][j], 0, 0, 0);
                acc[1][j] = __builtin_amdgcn_mfma_f32_16x16x32_bf16(ah1c, bc[j], acc[1][j], 0, 0, 0);
                acc[0][j] = __builtin_amdgcn_mfma_f32_16x16x32_bf16(al0c, bc[j], acc[0][j], 0, 0, 0);
                acc[1][j] = __builtin_amdgcn_mfma_f32_16x16x32_bf16(al1c, bc[j], acc[1][j], 0, 0, 0);
            }
            acc[0][7] = __builtin_amdgcn_mfma_f32_16x16x32_bf16(ah0c, bc[8], acc[0][7], 0, 0, 0);
            acc[1][7] = __builtin_amdgcn_mfma_f32_16x16x32_bf16(ah1c, bc[8], acc[1][7], 0, 0, 0);
        }
        if (kt + 1 < KT) {
            #pragma unroll
            for (int j = 0; j < 9; ++j) bc[j] = bn[j];
            ah0c = ah0n; al0c = al0n; ah1c = ah1n; al1c = al1n;
        }
    }

    // epilogue: C layout col = lane&15, row = (lane>>4)*4 + r  [m89-verified]
    #pragma unroll
    for (int mt = 0; mt < 2; ++mt) {
        int rowB = m0 + mt * 16 + (lane >> 4) * 4;
        if (wn == 0) {
            #pragma unroll
            for (int j = 0; j < 9; ++j) {
                int col = j * 16 + (lane & 15);
                #pragma unroll
                for (int r = 0; r < 4; ++r)
                    xpb[(size_t)(rowB + r) * D1 + col] = f2bf(acc[mt][j][r]);
            }
        } else {
            #pragma unroll
            for (int j = 0; j < 8; ++j) {
                int nt = 9 + j;
                int col = nt * 16 + (lane & 15);
                #pragma unroll
                for (int r = 0; r < 4; ++r) {
                    int row = rowB + r;
                    float v = acc[mt][j][r];
                    if (col < 256)      xpb[(size_t)row * D1 + col] = f2bf(v);
                    else if (col < 260) asrc[row * H + (col - 256)] = v;
                    else if (col < 264) adst[row * H + (col - 260)] = v;
                }
            }
        }
    }
}

// ---- node aggregation: one wave per node; HALF-WAVE PER EDGE (2 edges/step):
//      lane = 32*half + hl; lane holds 8 channels (uint4) of its half's edge.
//      All per-edge scalar ops amortize over 2 edges per instruction. ----
__global__ __launch_bounds__(256) void k_node(
    const unsigned* __restrict__ cnt, const int* __restrict__ slots,
    const float* __restrict__ asrc, const float* __restrict__ adst,
    const unsigned short* __restrict__ xp,   // bf16 [NT+1][256]
    const float* __restrict__ bias, const float* __restrict__ pw,
    const float* __restrict__ pb,
    unsigned short* __restrict__ hhi, unsigned short* __restrict__ hlo,
    float* __restrict__ out, int sec)
{
    int bid = blockIdx.x;
    int w = threadIdx.x >> 6, lane = threadIdx.x & 63;
    int half = lane >> 5;                     // which edge of the pair
    int hl   = lane & 31;                     // lane within half: ch 8*hl..8*hl+7
    int head = hl >> 3;                       // 8 lanes per head
    // graph g = bid&7 pinned to XCD g; 4 nodes per block (one per wave)
    int node = ((bid & 7) << 12) | (((bid >> 3) << 2) + w);

    int deg = (int)cnt[node];                 // >= 1 (self loop)
    int dp  = (deg + 1) & ~1;                 // pairs; slots padded/sentineled
    const int* sl = slots + (size_t)node * CAP;
    float adh = adst[node * H + head];
    const uint4* xp4 = (const uint4*)xp;      // 8 bf16 per lane

    float den = 0.f;
    float acc0 = 0.f, acc1 = 0.f, acc2 = 0.f, acc3 = 0.f,
          acc4 = 0.f, acc5 = 0.f, acc6 = 0.f, acc7 = 0.f;

    // 2-pair lookahead (4 edges in flight)
    int   s0 = sl[0 + half];                  // pre-scaled s*4
    int   s1 = sl[2 + half];
    float a0 = asrc[s0 + head];
    float a1 = asrc[s1 + head];
    uint4 v0 = xp4[(s0 << 3) + hl];
    uint4 v1 = xp4[(s1 << 3) + hl];

    for (int i = 0; i < dp; i += 2) {
        int   s2 = sl[i + 4 + half];
        float a2 = asrc[s2 + head];
        uint4 v2 = xp4[(s2 << 3) + hl];

        float l  = a0 + adh;
        float ev = __expf(fmaxf(l, 0.2f * l));
        den += ev;
        acc0 = fmaf(ev, __uint_as_float(v0.x << 16),         acc0);
        acc1 = fmaf(ev, __uint_as_float(v0.x & 0xFFFF0000u), acc1);
        acc2 = fmaf(ev, __uint_as_float(v0.y << 16),         acc2);
        acc3 = fmaf(ev, __uint_as_float(v0.y & 0xFFFF0000u), acc3);
        acc4 = fmaf(ev, __uint_as_float(v0.z << 16),         acc4);
        acc5 = fmaf(ev, __uint_as_float(v0.z & 0xFFFF0000u), acc5);
        acc6 = fmaf(ev, __uint_as_float(v0.w << 16),         acc6);
        acc7 = fmaf(ev, __uint_as_float(v0.w & 0xFFFF0000u), acc7);

        s0 = s1; a0 = a1; v0 = v1;
        s1 = s2; a1 = a2; v1 = v2;
    }

    // combine the two halves (lane l <-> l^32 hold same channels, different edges)
    den  += __shfl_xor(den, 32);
    acc0 += __shfl_xor(acc0, 32);
    acc1 += __shfl_xor(acc1, 32);
    acc2 += __shfl_xor(acc2, 32);
    acc3 += __shfl_xor(acc3, 32);
    acc4 += __shfl_xor(acc4, 32);
    acc5 += __shfl_xor(acc5, 32);
    acc6 += __shfl_xor(acc6, 32);
    acc7 += __shfl_xor(acc7, 32);

    float invd = 1.f / (den + 1e-16f);
    float4 b0 = reinterpret_cast<const float4*>(bias)[hl * 2];
    float4 b1 = reinterpret_cast<const float4*>(bias)[hl * 2 + 1];
    float4 p0 = reinterpret_cast<const float4*>(pw)[hl * 2];
    float4 p1 = reinterpret_cast<const float4*>(pw)[hl * 2 + 1];

    float h0 = fmaf(acc0, invd, b0.x), h1 = fmaf(acc1, invd, b0.y),
          h2 = fmaf(acc2, invd, b0.z), h3 = fmaf(acc3, invd, b0.w),
          h4 = fmaf(acc4, invd, b1.x), h5 = fmaf(acc5, invd, b1.y),
          h6 = fmaf(acc6, invd, b1.z), h7 = fmaf(acc7, invd, b1.w);
    h0 = h0 > 0.f ? h0 : __expf(h0) - 1.f;
    h1 = h1 > 0.f ? h1 : __expf(h1) - 1.f;
    h2 = h2 > 0.f ? h2 : __expf(h2) - 1.f;
    h3 = h3 > 0.f ? h3 : __expf(h3) - 1.f;
    h4 = h4 > 0.f ? h4 : __expf(h4) - 1.f;
    h5 = h5 > 0.f ? h5 : __expf(h5) - 1.f;
    h6 = h6 > 0.f ? h6 : __expf(h6) - 1.f;
    h7 = h7 > 0.f ? h7 : __expf(h7) - 1.f;

    if (hhi && half == 0) {
        unsigned short q0 = f2bf(h0), q1 = f2bf(h1), q2 = f2bf(h2), q3 = f2bf(h3),
                       q4 = f2bf(h4), q5 = f2bf(h5), q6 = f2bf(h6), q7 = f2bf(h7);
        uint4 hw, lw;
        hw.x = (unsigned)q0 | ((unsigned)q1 << 16);
        hw.y = (unsigned)q2 | ((unsigned)q3 << 16);
        hw.z = (unsigned)q4 | ((unsigned)q5 << 16);
        hw.w = (unsigned)q6 | ((unsigned)q7 << 16);
        lw.x = (unsigned)f2bf(h0 - bf2f(q0)) | ((unsigned)f2bf(h1 - bf2f(q1)) << 16);
        lw.y = (unsigned)f2bf(h2 - bf2f(q2)) | ((unsigned)f2bf(h3 - bf2f(q3)) << 16);
        lw.z = (unsigned)f2bf(h4 - bf2f(q4)) | ((unsigned)f2bf(h5 - bf2f(q5)) << 16);
        lw.w = (unsigned)f2bf(h6 - bf2f(q6)) | ((unsigned)f2bf(h7 - bf2f(q7)) << 16);
        reinterpret_cast<uint4*>(hhi)[node * 32 + hl] = hw;
        reinterpret_cast<uint4*>(hlo)[node * 32 + hl] = lw;
    }

    float p = h0 * p0.x + h1 * p0.y + h2 * p0.z + h3 * p0.w
            + h4 * p1.x + h5 * p1.y + h6 * p1.z + h7 * p1.w;
    #pragma unroll
    for (int o = 16; o; o >>= 1) p += __shfl_xor(p, o);
    if (lane == 0) {
        int b = node >> 12;
        int n = node & (N - 1);
        out[b * (3 * N) + sec * N + n] = p + pb[0];
    }
}

extern "C" void kernel_launch(void* const* d_in, const int* in_sizes, int n_in,
                              void* d_out, int out_size, void* d_ws, size_t ws_size,
                              hipStream_t stream) {
    const float* x   = (const float*)d_in[0];
    const int*   ei  = (const int*)d_in[1];
    const float* W1  = (const float*)d_in[2];
    const float* as1 = (const float*)d_in[3];
    const float* ad1 = (const float*)d_in[4];
    const float* b1  = (const float*)d_in[5];
    const float* W2  = (const float*)d_in[6];
    const float* as2 = (const float*)d_in[7];
    const float* ad2 = (const float*)d_in[8];
    const float* b2  = (const float*)d_in[9];
    const float* pw1 = (const float*)d_in[10];
    const float* pb1 = (const float*)d_in[11];
    const float* pw2 = (const float*)d_in[12];
    const float* pb2 = (const float*)d_in[13];
    float* out = (float*)d_out;

    // workspace layout (16B aligned blocks); xpb/asrc have +1 sentinel row
    unsigned short* xpb  = (unsigned short*)d_ws;             // (NT+1)*D1 bf16
    unsigned short* xhi  = xpb  + (size_t)(NT + 1) * D1;      // NT*FIN
    unsigned short* xlo  = xhi  + (size_t)NT * FIN;           // NT*FIN
    unsigned short* h1hi = xlo  + (size_t)NT * FIN;           // NT*D1
    unsigned short* h1lo = h1hi + (size_t)NT * D1;            // NT*D1
    float*    asrc   = (float*)(h1lo + (size_t)NT * D1);      // (NT+1)*H
    float*    adst   = asrc + (size_t)(NT + 1) * H;           // NT*H
    unsigned short* pB1 = (unsigned short*)(adst + (size_t)NT * H); // 4*18*64*8
    unsigned short* pB2 = pB1 + (size_t)4 * NSLOT * 64 * 8;         // 8*18*64*8
    unsigned* cnt    = (unsigned*)(pB2 + (size_t)8 * NSLOT * 64 * 8); // NT
    int*      slots  = (int*)(cnt + NT);                      // NT*CAP

    // 7 dispatches total, no hipMemset
    k_prep<<<182, 256, 0, stream>>>(W1, as1, ad1, W2, as2, ad2, pB1, pB2, cnt);
    k_combo<<<NT / 8, 256, 0, stream>>>(x, ei, xhi, xlo, out, cnt, slots);
    k_pad<<<NT / 256, 256, 0, stream>>>(cnt, slots, asrc, xpb);

    // ---------------- layer 1 (K = 128) ----------------
    k_mfma<128><<<NT / 64, 256, 0, stream>>>(xhi, xlo, pB1, xpb, asrc, adst);
    k_node<<<NT / 4, 256, 0, stream>>>(cnt, slots, asrc, adst, xpb,
                                       b1, pw1, pb1, h1hi, h1lo, out, 1);

    // ---------------- layer 2 (K = 256) ----------------
    k_mfma<256><<<NT / 64, 256, 0, stream>>>(h1hi, h1lo, pB2, xpb, asrc, adst);
    k_node<<<NT / 4, 256, 0, stream>>>(cnt, slots, asrc, adst, xpb,
                                       b2, pw2, pb2, nullptr, nullptr, out, 2);
}

// Round 11
// 142.307 us; speedup vs baseline: 1.4050x; 1.0558x over previous
//
#include <hip/hip_runtime.h>

typedef __attribute__((ext_vector_type(8))) short bf16x8;
typedef __attribute__((ext_vector_type(4))) float f32x4;
typedef __attribute__((ext_vector_type(2))) float pk2;

// Problem constants (from reference)
constexpr int B    = 8;
constexpr int N    = 4096;
constexpr int FIN  = 128;
constexpr int NT   = B * N;        // 32768
constexpr int H    = 4;
constexpr int C    = 64;
constexpr int D1   = H * C;        // 256
constexpr int E    = 524288;
constexpr int ETOT = E + NT;       // 557056
constexpr int NSLOT = 18;          // per-kt B slots: 0..16 = bh(nt0..16), 17 = blAtt(nt16)
constexpr int CAP  = 64;           // adjacency bucket capacity (max deg ~40, pad <= 63)

// bf16 round-to-nearest-even helpers
__device__ __forceinline__ unsigned short f2bf(float f) {
    unsigned u = __float_as_uint(f);
    return (unsigned short)((u + 0x7FFFu + ((u >> 16) & 1u)) >> 16);
}
__device__ __forceinline__ float bf2f(unsigned short b) {
    return __uint_as_float(((unsigned)b) << 16);
}

// ---- tiny: zero cnt + install sentinel rows (must precede combo's atomics) ----
__global__ __launch_bounds__(256) void k_zero(unsigned* __restrict__ cnt,
                                              float* __restrict__ asrc,
                                              unsigned short* __restrict__ xpb) {
    int i = blockIdx.x * 256 + threadIdx.x;
    cnt[i] = 0u;
    if (i < 4)  asrc[NT * H + i] = -1e30f;
    if (i < 64) reinterpret_cast<uint2*>(xpb)[(size_t)NT * 64 + i] = make_uint2(0u, 0u);
}

// ---- pack one layer's Bext = [W | Ws | Wd | 0] into per-kt slot layout ----
__device__ __forceinline__ void pack_body(
    const float* __restrict__ W, const float* __restrict__ as_,
    const float* __restrict__ ad_, unsigned short* __restrict__ pB, int g)
{
    int kt  = g / (NSLOT * 64);
    int rem = g % (NSLOT * 64);
    int slot = rem >> 6, l = rem & 63;
    int k0 = kt * 32 + 8 * (l >> 4);
    bool wantLo = (slot == 17);
    int nt = wantLo ? 16 : slot;
    int n  = nt * 16 + (l & 15);
    bf16x8 o;
    #pragma unroll
    for (int j = 0; j < 8; ++j) {
        int k = k0 + j;
        float v;
        if (n < 256) {
            v = W[k * D1 + n];
        } else if (n < 264) {
            int idx = n - 256, hh = idx & 3;
            const float* av = (idx < 4) ? as_ : ad_;
            float s = 0.f;
            #pragma unroll 8
            for (int c = 0; c < C; ++c) s += W[k * D1 + hh * C + c] * av[hh * C + c];
            v = s;
        } else {
            v = 0.f;
        }
        unsigned short hb = f2bf(v);
        o[j] = wantLo ? (short)f2bf(v - bf2f(hb)) : (short)hb;
    }
    *reinterpret_cast<bf16x8*>(pB + (size_t)g * 8) = o;
}

// ---- fused: x0 + split + adjacency build (bid<4096) | pack B1/B2 (bid>=4096) ----
__global__ __launch_bounds__(256) void k_combo(
    const float* __restrict__ x, const int* __restrict__ ei,
    unsigned short* __restrict__ hi, unsigned short* __restrict__ lo,
    float* __restrict__ out, unsigned* __restrict__ cnt, int* __restrict__ slots,
    const float* __restrict__ W1, const float* __restrict__ as1, const float* __restrict__ ad1,
    const float* __restrict__ W2, const float* __restrict__ as2, const float* __restrict__ ad2,
    unsigned short* __restrict__ pB1, unsigned short* __restrict__ pB2)
{
    int bid = blockIdx.x, t = threadIdx.x;

    if (bid >= NT / 8) {  // pack blocks
        int pb = bid - NT / 8;
        if (pb < 18) pack_body(W1, as1, ad1, pB1, pb * 256 + t);
        else         pack_body(W2, as2, ad2, pB2, (pb - 18) * 256 + t);
        return;
    }

    // part 1: x0 + split (8 nodes/block, 32 threads/node, float4 each)
    {
        int node = bid * 8 + (t >> 5);
        int q = t & 31;
        float4 v = reinterpret_cast<const float4*>(x)[node * 32 + q];
        ushort4 h, l;
        h.x = f2bf(v.x); l.x = f2bf(v.x - bf2f(h.x));
        h.y = f2bf(v.y); l.y = f2bf(v.y - bf2f(h.y));
        h.z = f2bf(v.z); l.z = f2bf(v.z - bf2f(h.z));
        h.w = f2bf(v.w); l.w = f2bf(v.w - bf2f(h.w));
        reinterpret_cast<ushort4*>(hi)[node * 32 + q] = h;
        reinterpret_cast<ushort4*>(lo)[node * 32 + q] = l;
        float s = v.x + v.y + v.z + v.w;
        #pragma unroll
        for (int o = 16; o; o >>= 1) s += __shfl_xor(s, o);
        if (q == 0) {
            int b = node >> 12;
            int n = node & (N - 1);
            out[b * (3 * N) + n] = s * (1.0f / 128.0f);
        }
    }

    // part 2: adjacency bucket build, slots hold PRE-SCALED src*H
    if (bid < ETOT / 256) {
        int e = bid * 256 + t;
        int s, d;
        if (e < E) { s = ei[e]; d = ei[E + e]; } else { s = d = e - E; }
        unsigned p = atomicAdd(cnt + d, 1u);
        slots[d * CAP + p] = s * 4;
    }
}

// ---- MFMA GEMM: C[NT x 264] = A[NT x K] * Bext, software-pipelined.
//      BM=64; 4 waves = 2 wm x 2 wn; wave: 2 m-tiles x 9 slots.
//      PAD=true: extra trailing blocks pad adjacency buckets with sentinels. ----
template <int K, bool PAD>
__global__ __launch_bounds__(256) void k_mfma(
    const unsigned short* __restrict__ Ahi, const unsigned short* __restrict__ Alo,
    const unsigned short* __restrict__ pB,
    unsigned short* __restrict__ xpb, float* __restrict__ asrc, float* __restrict__ adst,
    const unsigned* __restrict__ cnt, int* __restrict__ slots)
{
    constexpr int KT = K / 32;
    int t = threadIdx.x, lane = t & 63, w = t >> 6;

    if (PAD && blockIdx.x >= NT / 64) {   // bucket padding blocks
        int node = (blockIdx.x - NT / 64) * 256 + t;
        int deg = (int)cnt[node];
        int dpad = ((deg + 1) & ~1) + 14;  // covers 3-pair lookahead overshoot
        int* sl = slots + (size_t)node * CAP;
        for (int i = deg; i < dpad; ++i) sl[i] = NT * 4;
        return;
    }

    int wm = w & 1, wn = w >> 1;
    int m0 = blockIdx.x * 64 + wm * 32;
    int sBase = wn * 9;

    f32x4 acc[2][9];
    #pragma unroll
    for (int i = 0; i < 2; ++i)
        #pragma unroll
        for (int j = 0; j < 9; ++j)
            acc[i][j] = (f32x4){0.f, 0.f, 0.f, 0.f};

    int aRow = m0 + (lane & 15);
    int aCol = 8 * (lane >> 4);
    const unsigned short* a0h = Ahi + (size_t)aRow * K + aCol;
    const unsigned short* a0l = Alo + (size_t)aRow * K + aCol;
    const unsigned short* bp  = pB + ((size_t)sBase * 64 + lane) * 8;

    bf16x8 bc[9], bn[9];
    bf16x8 ah0c, al0c, ah1c, al1c, ah0n, al0n, ah1n, al1n;

    #pragma unroll
    for (int j = 0; j < 9; ++j) bc[j] = *reinterpret_cast<const bf16x8*>(bp + j * 512);
    ah0c = *reinterpret_cast<const bf16x8*>(a0h);
    al0c = *reinterpret_cast<const bf16x8*>(a0l);
    ah1c = *reinterpret_cast<const bf16x8*>(a0h + 16 * K);
    al1c = *reinterpret_cast<const bf16x8*>(a0l + 16 * K);

    #pragma unroll
    for (int kt = 0; kt < KT; ++kt) {
        if (kt + 1 < KT) {
            const unsigned short* bpn = bp + (size_t)(kt + 1) * NSLOT * 64 * 8;
            #pragma unroll
            for (int j = 0; j < 9; ++j) bn[j] = *reinterpret_cast<const bf16x8*>(bpn + j * 512);
            ah0n = *reinterpret_cast<const bf16x8*>(a0h + (kt + 1) * 32);
            al0n = *reinterpret_cast<const bf16x8*>(a0l + (kt + 1) * 32);
            ah1n = *reinterpret_cast<const bf16x8*>(a0h + 16 * K + (kt + 1) * 32);
            al1n = *reinterpret_cast<const bf16x8*>(a0l + 16 * K + (kt + 1) * 32);
        }
        __builtin_amdgcn_sched_barrier(0);   // keep prefetch loads ahead of MFMAs
        if (wn == 0) {
            #pragma unroll
            for (int j = 0; j < 9; ++j) {
                acc[0][j] = __builtin_amdgcn_mfma_f32_16x16x32_bf16(ah0c, bc[j], acc[0][j], 0, 0, 0);
                acc[1][j] = __builtin_amdgcn_mfma_f32_16x16x32_bf16(ah1c, bc[j], acc[1][j], 0, 0, 0);
                acc[0][j] = __builtin_amdgcn_mfma_f32_16x16x32_bf16(al0c, bc[j], acc[0][j], 0, 0, 0);
                acc[1][j] = __builtin_amdgcn_mfma_f32_16x16x32_bf16(al1c, bc[j], acc[1][j], 0, 0, 0);
            }
        } else {
            #pragma unroll
            for (int j = 0; j < 8; ++j) {
                acc[0][j] = __builtin_amdgcn_mfma_f32_16x16x32_bf16(ah0c, bc[j], acc[0][j], 0, 0, 0);
                acc[1][j] = __builtin_amdgcn_mfma_f32_16x16x32_bf16(ah1c, bc[j], acc[1][j], 0, 0, 0);
                acc[0][j] = __builtin_amdgcn_mfma_f32_16x16x32_bf16(al0c, bc[j], acc[0][j], 0, 0, 0);
                acc[1][j] = __builtin_amdgcn_mfma_f32_16x16x32_bf16(al1c, bc[j], acc[1][j], 0, 0, 0);
            }
            acc[0][7] = __builtin_amdgcn_mfma_f32_16x16x32_bf16(ah0c, bc[8], acc[0][7], 0, 0, 0);
            acc[1][7] = __builtin_amdgcn_mfma_f32_16x16x32_bf16(ah1c, bc[8], acc[1][7], 0, 0, 0);
        }
        if (kt + 1 < KT) {
            #pragma unroll
            for (int j = 0; j < 9; ++j) bc[j] = bn[j];
            ah0c = ah0n; al0c = al0n; ah1c = ah1n; al1c = al1n;
        }
    }

    // epilogue: C layout col = lane&15, row = (lane>>4)*4 + r  [m89-verified]
    #pragma unroll
    for (int mt = 0; mt < 2; ++mt) {
        int rowB = m0 + mt * 16 + (lane >> 4) * 4;
        if (wn == 0) {
            #pragma unroll
            for (int j = 0; j < 9; ++j) {
                int col = j * 16 + (lane & 15);
                #pragma unroll
                for (int r = 0; r < 4; ++r)
                    xpb[(size_t)(rowB + r) * D1 + col] = f2bf(acc[mt][j][r]);
            }
        } else {
            #pragma unroll
            for (int j = 0; j < 8; ++j) {
                int nt = 9 + j;
                int col = nt * 16 + (lane & 15);
                #pragma unroll
                for (int r = 0; r < 4; ++r) {
                    int row = rowB + r;
                    float v = acc[mt][j][r];
                    if (col < 256)      xpb[(size_t)row * D1 + col] = f2bf(v);
                    else if (col < 260) asrc[row * H + (col - 256)] = v;
                    else if (col < 264) adst[row * H + (col - 260)] = v;
                }
            }
        }
    }
}

// ---- node aggregation: one wave per node; half-wave per edge (2 edges/step);
//      packed-f32 FMA (v_pk_fma_f32) + 3-slot circular prefetch (6 edges in flight) ----
__global__ __launch_bounds__(256) void k_node(
    const unsigned* __restrict__ cnt, const int* __restrict__ slots,
    const float* __restrict__ asrc, const float* __restrict__ adst,
    const unsigned short* __restrict__ xp,   // bf16 [NT+1][256]
    const float* __restrict__ bias, const float* __restrict__ pw,
    const float* __restrict__ pb,
    unsigned short* __restrict__ hhi, unsigned short* __restrict__ hlo,
    float* __restrict__ out, int sec)
{
    int bid = blockIdx.x;
    int w = threadIdx.x >> 6, lane = threadIdx.x & 63;
    int half = lane >> 5;                     // which edge of the pair
    int hl   = lane & 31;                     // lane within half: ch 8*hl..8*hl+7
    int head = hl >> 3;                       // 8 lanes per head
    // graph g = bid&7 pinned to XCD g; 4 nodes per block (one per wave)
    int node = ((bid & 7) << 12) | (((bid >> 3) << 2) + w);

    int deg = (int)cnt[node];                 // >= 1 (self loop)
    int dp  = (deg + 1) & ~1;                 // pair-rounded; overshoot hits sentinels
    const int* sl = slots + (size_t)node * CAP;
    float adh = adst[node * H + head];
    const uint4* xp4 = (const uint4*)xp;      // 8 bf16 per lane

    float den = 0.f;
    pk2 acc01 = {0.f, 0.f}, acc23 = {0.f, 0.f}, acc45 = {0.f, 0.f}, acc67 = {0.f, 0.f};

    #define PROC(aa, vv)                                                     \
    {                                                                        \
        float l  = aa + adh;                                                 \
        float ev = __expf(fmaxf(l, 0.2f * l));                               \
        den += ev;                                                           \
        pk2 e2 = {ev, ev};                                                   \
        pk2 t01 = {__uint_as_float(vv.x << 16), __uint_as_float(vv.x & 0xFFFF0000u)}; \
        pk2 t23 = {__uint_as_float(vv.y << 16), __uint_as_float(vv.y & 0xFFFF0000u)}; \
        pk2 t45 = {__uint_as_float(vv.z << 16), __uint_as_float(vv.z & 0xFFFF0000u)}; \
        pk2 t67 = {__uint_as_float(vv.w << 16), __uint_as_float(vv.w & 0xFFFF0000u)}; \
        acc01 = __builtin_elementwise_fma(e2, t01, acc01);                   \
        acc23 = __builtin_elementwise_fma(e2, t23, acc23);                   \
        acc45 = __builtin_elementwise_fma(e2, t45, acc45);                   \
        acc67 = __builtin_elementwise_fma(e2, t67, acc67);                   \
    }

    // 3-slot circular prefetch: pairs 0,2,4 preloaded; prefetch i+6 before use
    int   s_;
    float aX, aY, aZ, a_;
    uint4 vX, vY, vZ, v_;
    s_ = sl[0 + half]; aX = asrc[s_ + head]; vX = xp4[(s_ << 3) + hl];
    s_ = sl[2 + half]; aY = asrc[s_ + head]; vY = xp4[(s_ << 3) + hl];
    s_ = sl[4 + half]; aZ = asrc[s_ + head]; vZ = xp4[(s_ << 3) + hl];

    for (int i = 0; i < dp; i += 6) {
        s_ = sl[i + 6 + half];  a_ = asrc[s_ + head]; v_ = xp4[(s_ << 3) + hl];
        PROC(aX, vX); aX = a_; vX = v_;
        s_ = sl[i + 8 + half];  a_ = asrc[s_ + head]; v_ = xp4[(s_ << 3) + hl];
        PROC(aY, vY); aY = a_; vY = v_;
        s_ = sl[i + 10 + half]; a_ = asrc[s_ + head]; v_ = xp4[(s_ << 3) + hl];
        PROC(aZ, vZ); aZ = a_; vZ = v_;
    }
    #undef PROC

    // combine the two halves (lane l <-> l^32 hold same channels, different edges)
    den      += __shfl_xor(den, 32);
    acc01[0] += __shfl_xor(acc01[0], 32);
    acc01[1] += __shfl_xor(acc01[1], 32);
    acc23[0] += __shfl_xor(acc23[0], 32);
    acc23[1] += __shfl_xor(acc23[1], 32);
    acc45[0] += __shfl_xor(acc45[0], 32);
    acc45[1] += __shfl_xor(acc45[1], 32);
    acc67[0] += __shfl_xor(acc67[0], 32);
    acc67[1] += __shfl_xor(acc67[1], 32);

    float invd = 1.f / (den + 1e-16f);
    float4 b0 = reinterpret_cast<const float4*>(bias)[hl * 2];
    float4 b1 = reinterpret_cast<const float4*>(bias)[hl * 2 + 1];
    float4 p0 = reinterpret_cast<const float4*>(pw)[hl * 2];
    float4 p1 = reinterpret_cast<const float4*>(pw)[hl * 2 + 1];

    float h0 = fmaf(acc01[0], invd, b0.x), h1 = fmaf(acc01[1], invd, b0.y),
          h2 = fmaf(acc23[0], invd, b0.z), h3 = fmaf(acc23[1], invd, b0.w),
          h4 = fmaf(acc45[0], invd, b1.x), h5 = fmaf(acc45[1], invd, b1.y),
          h6 = fmaf(acc67[0], invd, b1.z), h7 = fmaf(acc67[1], invd, b1.w);
    h0 = h0 > 0.f ? h0 : __expf(h0) - 1.f;
    h1 = h1 > 0.f ? h1 : __expf(h1) - 1.f;
    h2 = h2 > 0.f ? h2 : __expf(h2) - 1.f;
    h3 = h3 > 0.f ? h3 : __expf(h3) - 1.f;
    h4 = h4 > 0.f ? h4 : __expf(h4) - 1.f;
    h5 = h5 > 0.f ? h5 : __expf(h5) - 1.f;
    h6 = h6 > 0.f ? h6 : __expf(h6) - 1.f;
    h7 = h7 > 0.f ? h7 : __expf(h7) - 1.f;

    if (hhi && half == 0) {
        unsigned short q0 = f2bf(h0), q1 = f2bf(h1), q2 = f2bf(h2), q3 = f2bf(h3),
                       q4 = f2bf(h4), q5 = f2bf(h5), q6 = f2bf(h6), q7 = f2bf(h7);
        uint4 hw, lw;
        hw.x = (unsigned)q0 | ((unsigned)q1 << 16);
        hw.y = (unsigned)q2 | ((unsigned)q3 << 16);
        hw.z = (unsigned)q4 | ((unsigned)q5 << 16);
        hw.w = (unsigned)q6 | ((unsigned)q7 << 16);
        lw.x = (unsigned)f2bf(h0 - bf2f(q0)) | ((unsigned)f2bf(h1 - bf2f(q1)) << 16);
        lw.y = (unsigned)f2bf(h2 - bf2f(q2)) | ((unsigned)f2bf(h3 - bf2f(q3)) << 16);
        lw.z = (unsigned)f2bf(h4 - bf2f(q4)) | ((unsigned)f2bf(h5 - bf2f(q5)) << 16);
        lw.w = (unsigned)f2bf(h6 - bf2f(q6)) | ((unsigned)f2bf(h7 - bf2f(q7)) << 16);
        reinterpret_cast<uint4*>(hhi)[node * 32 + hl] = hw;
        reinterpret_cast<uint4*>(hlo)[node * 32 + hl] = lw;
    }

    float p = h0 * p0.x + h1 * p0.y + h2 * p0.z + h3 * p0.w
            + h4 * p1.x + h5 * p1.y + h6 * p1.z + h7 * p1.w;
    #pragma unroll
    for (int o = 16; o; o >>= 1) p += __shfl_xor(p, o);
    if (lane == 0) {
        int b = node >> 12;
        int n = node & (N - 1);
        out[b * (3 * N) + sec * N + n] = p + pb[0];
    }
}

extern "C" void kernel_launch(void* const* d_in, const int* in_sizes, int n_in,
                              void* d_out, int out_size, void* d_ws, size_t ws_size,
                              hipStream_t stream) {
    const float* x   = (const float*)d_in[0];
    const int*   ei  = (const int*)d_in[1];
    const float* W1  = (const float*)d_in[2];
    const float* as1 = (const float*)d_in[3];
    const float* ad1 = (const float*)d_in[4];
    const float* b1  = (const float*)d_in[5];
    const float* W2  = (const float*)d_in[6];
    const float* as2 = (const float*)d_in[7];
    const float* ad2 = (const float*)d_in[8];
    const float* b2  = (const float*)d_in[9];
    const float* pw1 = (const float*)d_in[10];
    const float* pb1 = (const float*)d_in[11];
    const float* pw2 = (const float*)d_in[12];
    const float* pb2 = (const float*)d_in[13];
    float* out = (float*)d_out;

    // workspace layout (16B aligned blocks); xpb/asrc have +1 sentinel row
    unsigned short* xpb  = (unsigned short*)d_ws;             // (NT+1)*D1 bf16
    unsigned short* xhi  = xpb  + (size_t)(NT + 1) * D1;      // NT*FIN
    unsigned short* xlo  = xhi  + (size_t)NT * FIN;           // NT*FIN
    unsigned short* h1hi = xlo  + (size_t)NT * FIN;           // NT*D1
    unsigned short* h1lo = h1hi + (size_t)NT * D1;            // NT*D1
    float*    asrc   = (float*)(h1lo + (size_t)NT * D1);      // (NT+1)*H
    float*    adst   = asrc + (size_t)(NT + 1) * H;           // NT*H
    unsigned short* pB1 = (unsigned short*)(adst + (size_t)NT * H); // 4*18*64*8
    unsigned short* pB2 = pB1 + (size_t)4 * NSLOT * 64 * 8;         // 8*18*64*8
    unsigned* cnt    = (unsigned*)(pB2 + (size_t)8 * NSLOT * 64 * 8); // NT
    int*      slots  = (int*)(cnt + NT);                      // NT*CAP

    // 6 dispatches total
    k_zero<<<NT / 256, 256, 0, stream>>>(cnt, asrc, xpb);
    k_combo<<<NT / 8 + 54, 256, 0, stream>>>(x, ei, xhi, xlo, out, cnt, slots,
                                             W1, as1, ad1, W2, as2, ad2, pB1, pB2);

    // ---------------- layer 1 (K = 128) ----------------
    k_mfma<128, true><<<NT / 64 + NT / 256, 256, 0, stream>>>(
        xhi, xlo, pB1, xpb, asrc, adst, cnt, slots);
    k_node<<<NT / 4, 256, 0, stream>>>(cnt, slots, asrc, adst, xpb,
                                       b1, pw1, pb1, h1hi, h1lo, out, 1);

    // ---------------- layer 2 (K = 256) ----------------
    k_mfma<256, false><<<NT / 64, 256, 0, stream>>>(
        h1hi, h1lo, pB2, xpb, asrc, adst, cnt, slots);
    k_node<<<NT / 4, 256, 0, stream>>>(cnt, slots, asrc, adst, xpb,
                                       b2, pw2, pb2, nullptr, nullptr, out, 2);
}

// Round 12
// 133.742 us; speedup vs baseline: 1.4949x; 1.0640x over previous
//
#include <hip/hip_runtime.h>

typedef __attribute__((ext_vector_type(8))) short bf16x8;
typedef __attribute__((ext_vector_type(4))) float f32x4;
typedef __attribute__((ext_vector_type(2))) float pk2;

// Problem constants (from reference)
constexpr int B    = 8;
constexpr int N    = 4096;
constexpr int FIN  = 128;
constexpr int NT   = B * N;        // 32768
constexpr int H    = 4;
constexpr int C    = 64;
constexpr int D1   = H * C;        // 256
constexpr int E    = 524288;
constexpr int ETOT = E + NT;       // 557056
constexpr int NSLOT = 18;          // per-kt B slots: 0..16 = bh(nt0..16), 17 = blAtt(nt16)
constexpr int CAP  = 64;           // adjacency bucket capacity (max deg ~40, pad <= 63)

// bf16 round-to-nearest-even helpers
__device__ __forceinline__ unsigned short f2bf(float f) {
    unsigned u = __float_as_uint(f);
    return (unsigned short)((u + 0x7FFFu + ((u >> 16) & 1u)) >> 16);
}
__device__ __forceinline__ float bf2f(unsigned short b) {
    return __uint_as_float(((unsigned)b) << 16);
}

// ---- zero cnt + sentinels; XCD-pinned: graph g's counters zeroed on XCD g ----
__global__ __launch_bounds__(256) void k_zero(unsigned* __restrict__ cnt,
                                              float* __restrict__ asrc,
                                              unsigned short* __restrict__ xpb) {
    int g = blockIdx.x & 7, j = blockIdx.x >> 3;         // 128 blocks: 16/graph
    int i = (g << 12) + (j << 8) + threadIdx.x;
    cnt[i] = 0u;
    if (i < 4)  asrc[NT * H + i] = -1e30f;
    if (i < 64) reinterpret_cast<uint2*>(xpb)[(size_t)NT * 64 + i] = make_uint2(0u, 0u);
}

// ---- pack one layer's Bext = [W | Ws | Wd | 0] into per-kt slot layout ----
__device__ __forceinline__ void pack_body(
    const float* __restrict__ W, const float* __restrict__ as_,
    const float* __restrict__ ad_, unsigned short* __restrict__ pB, int g)
{
    int kt  = g / (NSLOT * 64);
    int rem = g % (NSLOT * 64);
    int slot = rem >> 6, l = rem & 63;
    int k0 = kt * 32 + 8 * (l >> 4);
    bool wantLo = (slot == 17);
    int nt = wantLo ? 16 : slot;
    int n  = nt * 16 + (l & 15);
    bf16x8 o;
    #pragma unroll
    for (int j = 0; j < 8; ++j) {
        int k = k0 + j;
        float v;
        if (n < 256) {
            v = W[k * D1 + n];
        } else if (n < 264) {
            int idx = n - 256, hh = idx & 3;
            const float* av = (idx < 4) ? as_ : ad_;
            float s = 0.f;
            #pragma unroll 8
            for (int c = 0; c < C; ++c) s += W[k * D1 + hh * C + c] * av[hh * C + c];
            v = s;
        } else {
            v = 0.f;
        }
        unsigned short hb = f2bf(v);
        o[j] = wantLo ? (short)f2bf(v - bf2f(hb)) : (short)hb;
    }
    *reinterpret_cast<bf16x8*>(pB + (size_t)g * 8) = o;
}

// ---- fused: pack (bid<54) | x0 + split + adjacency build, ALL XCD-PINNED:
//      block nb handles graph nb&7 only (nodes AND edges), so cnt/slots/hi/lo
//      lines of graph g live exclusively in XCD g's L2. ----
__global__ __launch_bounds__(256) void k_combo(
    const float* __restrict__ x, const int* __restrict__ ei,
    unsigned short* __restrict__ hi, unsigned short* __restrict__ lo,
    float* __restrict__ out, unsigned* __restrict__ cnt, int* __restrict__ slots,
    const float* __restrict__ W1, const float* __restrict__ as1, const float* __restrict__ ad1,
    const float* __restrict__ W2, const float* __restrict__ as2, const float* __restrict__ ad2,
    unsigned short* __restrict__ pB1, unsigned short* __restrict__ pB2)
{
    int bid = blockIdx.x, t = threadIdx.x;

    if (bid < 54) {  // pack blocks (front of grid)
        if (bid < 18) pack_body(W1, as1, ad1, pB1, bid * 256 + t);
        else          pack_body(W2, as2, ad2, pB2, (bid - 18) * 256 + t);
        return;
    }

    int nb = bid - 54;                        // 0..4095
    int g  = nb & 7, loc = nb >> 3;           // graph g -> XCD g; loc 0..511

    // part 1: x0 + split for 8 nodes of graph g
    {
        int node = (g << 12) + (loc << 3) + (t >> 5);
        int q = t & 31;
        float4 v = reinterpret_cast<const float4*>(x)[node * 32 + q];
        ushort4 h, l;
        h.x = f2bf(v.x); l.x = f2bf(v.x - bf2f(h.x));
        h.y = f2bf(v.y); l.y = f2bf(v.y - bf2f(h.y));
        h.z = f2bf(v.z); l.z = f2bf(v.z - bf2f(h.z));
        h.w = f2bf(v.w); l.w = f2bf(v.w - bf2f(h.w));
        reinterpret_cast<ushort4*>(hi)[node * 32 + q] = h;
        reinterpret_cast<ushort4*>(lo)[node * 32 + q] = l;
        float s = v.x + v.y + v.z + v.w;
        #pragma unroll
        for (int o = 16; o; o >>= 1) s += __shfl_xor(s, o);
        if (q == 0) {
            int n = node & (N - 1);
            out[g * (3 * N) + n] = s * (1.0f / 128.0f);
        }
    }

    // part 2: adjacency build for graph g's edges only (edge list is graph-sorted:
    // main edges: 256 blocks/graph; self-loops: 16 blocks/graph)
    if (nb < 2176) {
        int eb;
        if (nb < 2048) eb = (g << 8) + (nb >> 3);                 // main edges
        else           eb = 2048 + (g << 4) + ((nb - 2048) >> 3); // self-loops
        int e = eb * 256 + t;
        int s, d;
        if (e < E) { s = ei[e]; d = ei[E + e]; } else { s = d = e - E; }
        unsigned p = atomicAdd(cnt + d, 1u);
        slots[d * CAP + p] = s * 4;
    }
}

// ---- MFMA GEMM: C[NT x 264] = A[NT x K] * Bext, software-pipelined, XCD-pinned.
//      BM=64; 4 waves = 2 wm x 2 wn; wave: 2 m-tiles x 9 slots. ----
template <int K, bool PAD>
__global__ __launch_bounds__(256) void k_mfma(
    const unsigned short* __restrict__ Ahi, const unsigned short* __restrict__ Alo,
    const unsigned short* __restrict__ pB,
    unsigned short* __restrict__ xpb, float* __restrict__ asrc, float* __restrict__ adst,
    const unsigned* __restrict__ cnt, int* __restrict__ slots)
{
    constexpr int KT = K / 32;
    int t = threadIdx.x, lane = t & 63, w = t >> 6;

    if (PAD && blockIdx.x >= NT / 64) {   // bucket padding blocks (XCD-pinned)
        int bl = blockIdx.x - NT / 64;    // 128 blocks: 16/graph
        int node = ((bl & 7) << 12) + ((bl >> 3) << 8) + t;
        int deg = (int)cnt[node];
        int dpad = ((deg + 1) & ~1) + 14;  // covers 3-pair lookahead overshoot
        int* sl = slots + (size_t)node * CAP;
        for (int i = deg; i < dpad; ++i) sl[i] = NT * 4;
        return;
    }

    int wm = w & 1, wn = w >> 1;
    // graph (bid&7) -> XCD (bid&7): rows of graph g computed on XCD g
    int m0 = ((blockIdx.x & 7) << 12) + ((blockIdx.x >> 3) << 6) + wm * 32;
    int sBase = wn * 9;

    f32x4 acc[2][9];
    #pragma unroll
    for (int i = 0; i < 2; ++i)
        #pragma unroll
        for (int j = 0; j < 9; ++j)
            acc[i][j] = (f32x4){0.f, 0.f, 0.f, 0.f};

    int aRow = m0 + (lane & 15);
    int aCol = 8 * (lane >> 4);
    const unsigned short* a0h = Ahi + (size_t)aRow * K + aCol;
    const unsigned short* a0l = Alo + (size_t)aRow * K + aCol;
    const unsigned short* bp  = pB + ((size_t)sBase * 64 + lane) * 8;

    bf16x8 bc[9], bn[9];
    bf16x8 ah0c, al0c, ah1c, al1c, ah0n, al0n, ah1n, al1n;

    #pragma unroll
    for (int j = 0; j < 9; ++j) bc[j] = *reinterpret_cast<const bf16x8*>(bp + j * 512);
    ah0c = *reinterpret_cast<const bf16x8*>(a0h);
    al0c = *reinterpret_cast<const bf16x8*>(a0l);
    ah1c = *reinterpret_cast<const bf16x8*>(a0h + 16 * K);
    al1c = *reinterpret_cast<const bf16x8*>(a0l + 16 * K);

    #pragma unroll
    for (int kt = 0; kt < KT; ++kt) {
        if (kt + 1 < KT) {
            const unsigned short* bpn = bp + (size_t)(kt + 1) * NSLOT * 64 * 8;
            #pragma unroll
            for (int j = 0; j < 9; ++j) bn[j] = *reinterpret_cast<const bf16x8*>(bpn + j * 512);
            ah0n = *reinterpret_cast<const bf16x8*>(a0h + (kt + 1) * 32);
            al0n = *reinterpret_cast<const bf16x8*>(a0l + (kt + 1) * 32);
            ah1n = *reinterpret_cast<const bf16x8*>(a0h + 16 * K + (kt + 1) * 32);
            al1n = *reinterpret_cast<const bf16x8*>(a0l + 16 * K + (kt + 1) * 32);
        }
        __builtin_amdgcn_sched_barrier(0);   // keep prefetch loads ahead of MFMAs
        if (wn == 0) {
            #pragma unroll
            for (int j = 0; j < 9; ++j) {
                acc[0][j] = __builtin_amdgcn_mfma_f32_16x16x32_bf16(ah0c, bc[j], acc[0][j], 0, 0, 0);
                acc[1][j] = __builtin_amdgcn_mfma_f32_16x16x32_bf16(ah1c, bc[j], acc[1][j], 0, 0, 0);
                acc[0][j] = __builtin_amdgcn_mfma_f32_16x16x32_bf16(al0c, bc[j], acc[0][j], 0, 0, 0);
                acc[1][j] = __builtin_amdgcn_mfma_f32_16x16x32_bf16(al1c, bc[j], acc[1][j], 0, 0, 0);
            }
        } else {
            #pragma unroll
            for (int j = 0; j < 8; ++j) {
                acc[0][j] = __builtin_amdgcn_mfma_f32_16x16x32_bf16(ah0c, bc[j], acc[0][j], 0, 0, 0);
                acc[1][j] = __builtin_amdgcn_mfma_f32_16x16x32_bf16(ah1c, bc[j], acc[1][j], 0, 0, 0);
                acc[0][j] = __builtin_amdgcn_mfma_f32_16x16x32_bf16(al0c, bc[j], acc[0][j], 0, 0, 0);
                acc[1][j] = __builtin_amdgcn_mfma_f32_16x16x32_bf16(al1c, bc[j], acc[1][j], 0, 0, 0);
            }
            acc[0][7] = __builtin_amdgcn_mfma_f32_16x16x32_bf16(ah0c, bc[8], acc[0][7], 0, 0, 0);
            acc[1][7] = __builtin_amdgcn_mfma_f32_16x16x32_bf16(ah1c, bc[8], acc[1][7], 0, 0, 0);
        }
        if (kt + 1 < KT) {
            #pragma unroll
            for (int j = 0; j < 9; ++j) bc[j] = bn[j];
            ah0c = ah0n; al0c = al0n; ah1c = ah1n; al1c = al1n;
        }
    }

    // epilogue: C layout col = lane&15, row = (lane>>4)*4 + r  [m89-verified]
    #pragma unroll
    for (int mt = 0; mt < 2; ++mt) {
        int rowB = m0 + mt * 16 + (lane >> 4) * 4;
        if (wn == 0) {
            #pragma unroll
            for (int j = 0; j < 9; ++j) {
                int col = j * 16 + (lane & 15);
                #pragma unroll
                for (int r = 0; r < 4; ++r)
                    xpb[(size_t)(rowB + r) * D1 + col] = f2bf(acc[mt][j][r]);
            }
        } else {
            #pragma unroll
            for (int j = 0; j < 8; ++j) {
                int nt = 9 + j;
                int col = nt * 16 + (lane & 15);
                #pragma unroll
                for (int r = 0; r < 4; ++r) {
                    int row = rowB + r;
                    float v = acc[mt][j][r];
                    if (col < 256)      xpb[(size_t)row * D1 + col] = f2bf(v);
                    else if (col < 260) asrc[row * H + (col - 256)] = v;
                    else if (col < 264) adst[row * H + (col - 260)] = v;
                }
            }
        }
    }
}

// ---- node aggregation: one wave per node; half-wave per edge (2 edges/step);
//      packed-f32 FMA + 3-slot circular prefetch (6 edges in flight) ----
__global__ __launch_bounds__(256) void k_node(
    const unsigned* __restrict__ cnt, const int* __restrict__ slots,
    const float* __restrict__ asrc, const float* __restrict__ adst,
    const unsigned short* __restrict__ xp,   // bf16 [NT+1][256]
    const float* __restrict__ bias, const float* __restrict__ pw,
    const float* __restrict__ pb,
    unsigned short* __restrict__ hhi, unsigned short* __restrict__ hlo,
    float* __restrict__ out, int sec)
{
    int bid = blockIdx.x;
    int w = threadIdx.x >> 6, lane = threadIdx.x & 63;
    int half = lane >> 5;                     // which edge of the pair
    int hl   = lane & 31;                     // lane within half: ch 8*hl..8*hl+7
    int head = hl >> 3;                       // 8 lanes per head
    // graph g = bid&7 pinned to XCD g; 4 nodes per block (one per wave)
    int node = ((bid & 7) << 12) | (((bid >> 3) << 2) + w);

    int deg = (int)cnt[node];                 // >= 1 (self loop)
    int dp  = (deg + 1) & ~1;                 // pair-rounded; overshoot hits sentinels
    const int* sl = slots + (size_t)node * CAP;
    float adh = adst[node * H + head];
    const uint4* xp4 = (const uint4*)xp;      // 8 bf16 per lane

    float den = 0.f;
    pk2 acc01 = {0.f, 0.f}, acc23 = {0.f, 0.f}, acc45 = {0.f, 0.f}, acc67 = {0.f, 0.f};

    #define PROC(aa, vv)                                                     \
    {                                                                        \
        float l  = aa + adh;                                                 \
        float ev = __expf(fmaxf(l, 0.2f * l));                               \
        den += ev;                                                           \
        pk2 e2 = {ev, ev};                                                   \
        pk2 t01 = {__uint_as_float(vv.x << 16), __uint_as_float(vv.x & 0xFFFF0000u)}; \
        pk2 t23 = {__uint_as_float(vv.y << 16), __uint_as_float(vv.y & 0xFFFF0000u)}; \
        pk2 t45 = {__uint_as_float(vv.z << 16), __uint_as_float(vv.z & 0xFFFF0000u)}; \
        pk2 t67 = {__uint_as_float(vv.w << 16), __uint_as_float(vv.w & 0xFFFF0000u)}; \
        acc01 = __builtin_elementwise_fma(e2, t01, acc01);                   \
        acc23 = __builtin_elementwise_fma(e2, t23, acc23);                   \
        acc45 = __builtin_elementwise_fma(e2, t45, acc45);                   \
        acc67 = __builtin_elementwise_fma(e2, t67, acc67);                   \
    }

    // 3-slot circular prefetch: pairs 0,2,4 preloaded; prefetch i+6 before use
    int   s_;
    float aX, aY, aZ, a_;
    uint4 vX, vY, vZ, v_;
    s_ = sl[0 + half]; aX = asrc[s_ + head]; vX = xp4[(s_ << 3) + hl];
    s_ = sl[2 + half]; aY = asrc[s_ + head]; vY = xp4[(s_ << 3) + hl];
    s_ = sl[4 + half]; aZ = asrc[s_ + head]; vZ = xp4[(s_ << 3) + hl];

    for (int i = 0; i < dp; i += 6) {
        s_ = sl[i + 6 + half];  a_ = asrc[s_ + head]; v_ = xp4[(s_ << 3) + hl];
        PROC(aX, vX); aX = a_; vX = v_;
        s_ = sl[i + 8 + half];  a_ = asrc[s_ + head]; v_ = xp4[(s_ << 3) + hl];
        PROC(aY, vY); aY = a_; vY = v_;
        s_ = sl[i + 10 + half]; a_ = asrc[s_ + head]; v_ = xp4[(s_ << 3) + hl];
        PROC(aZ, vZ); aZ = a_; vZ = v_;
    }
    #undef PROC

    // combine the two halves (lane l <-> l^32 hold same channels, different edges)
    den      += __shfl_xor(den, 32);
    acc01[0] += __shfl_xor(acc01[0], 32);
    acc01[1] += __shfl_xor(acc01[1], 32);
    acc23[0] += __shfl_xor(acc23[0], 32);
    acc23[1] += __shfl_xor(acc23[1], 32);
    acc45[0] += __shfl_xor(acc45[0], 32);
    acc45[1] += __shfl_xor(acc45[1], 32);
    acc67[0] += __shfl_xor(acc67[0], 32);
    acc67[1] += __shfl_xor(acc67[1], 32);

    float invd = 1.f / (den + 1e-16f);
    float4 b0 = reinterpret_cast<const float4*>(bias)[hl * 2];
    float4 b1 = reinterpret_cast<const float4*>(bias)[hl * 2 + 1];
    float4 p0 = reinterpret_cast<const float4*>(pw)[hl * 2];
    float4 p1 = reinterpret_cast<const float4*>(pw)[hl * 2 + 1];

    float h0 = fmaf(acc01[0], invd, b0.x), h1 = fmaf(acc01[1], invd, b0.y),
          h2 = fmaf(acc23[0], invd, b0.z), h3 = fmaf(acc23[1], invd, b0.w),
          h4 = fmaf(acc45[0], invd, b1.x), h5 = fmaf(acc45[1], invd, b1.y),
          h6 = fmaf(acc67[0], invd, b1.z), h7 = fmaf(acc67[1], invd, b1.w);
    h0 = h0 > 0.f ? h0 : __expf(h0) - 1.f;
    h1 = h1 > 0.f ? h1 : __expf(h1) - 1.f;
    h2 = h2 > 0.f ? h2 : __expf(h2) - 1.f;
    h3 = h3 > 0.f ? h3 : __expf(h3) - 1.f;
    h4 = h4 > 0.f ? h4 : __expf(h4) - 1.f;
    h5 = h5 > 0.f ? h5 : __expf(h5) - 1.f;
    h6 = h6 > 0.f ? h6 : __expf(h6) - 1.f;
    h7 = h7 > 0.f ? h7 : __expf(h7) - 1.f;

    if (hhi && half == 0) {
        unsigned short q0 = f2bf(h0), q1 = f2bf(h1), q2 = f2bf(h2), q3 = f2bf(h3),
                       q4 = f2bf(h4), q5 = f2bf(h5), q6 = f2bf(h6), q7 = f2bf(h7);
        uint4 hw, lw;
        hw.x = (unsigned)q0 | ((unsigned)q1 << 16);
        hw.y = (unsigned)q2 | ((unsigned)q3 << 16);
        hw.z = (unsigned)q4 | ((unsigned)q5 << 16);
        hw.w = (unsigned)q6 | ((unsigned)q7 << 16);
        lw.x = (unsigned)f2bf(h0 - bf2f(q0)) | ((unsigned)f2bf(h1 - bf2f(q1)) << 16);
        lw.y = (unsigned)f2bf(h2 - bf2f(q2)) | ((unsigned)f2bf(h3 - bf2f(q3)) << 16);
        lw.z = (unsigned)f2bf(h4 - bf2f(q4)) | ((unsigned)f2bf(h5 - bf2f(q5)) << 16);
        lw.w = (unsigned)f2bf(h6 - bf2f(q6)) | ((unsigned)f2bf(h7 - bf2f(q7)) << 16);
        reinterpret_cast<uint4*>(hhi)[node * 32 + hl] = hw;
        reinterpret_cast<uint4*>(hlo)[node * 32 + hl] = lw;
    }

    float p = h0 * p0.x + h1 * p0.y + h2 * p0.z + h3 * p0.w
            + h4 * p1.x + h5 * p1.y + h6 * p1.z + h7 * p1.w;
    #pragma unroll
    for (int o = 16; o; o >>= 1) p += __shfl_xor(p, o);
    if (lane == 0) {
        int b = node >> 12;
        int n = node & (N - 1);
        out[b * (3 * N) + sec * N + n] = p + pb[0];
    }
}

extern "C" void kernel_launch(void* const* d_in, const int* in_sizes, int n_in,
                              void* d_out, int out_size, void* d_ws, size_t ws_size,
                              hipStream_t stream) {
    const float* x   = (const float*)d_in[0];
    const int*   ei  = (const int*)d_in[1];
    const float* W1  = (const float*)d_in[2];
    const float* as1 = (const float*)d_in[3];
    const float* ad1 = (const float*)d_in[4];
    const float* b1  = (const float*)d_in[5];
    const float* W2  = (const float*)d_in[6];
    const float* as2 = (const float*)d_in[7];
    const float* ad2 = (const float*)d_in[8];
    const float* b2  = (const float*)d_in[9];
    const float* pw1 = (const float*)d_in[10];
    const float* pb1 = (const float*)d_in[11];
    const float* pw2 = (const float*)d_in[12];
    const float* pb2 = (const float*)d_in[13];
    float* out = (float*)d_out;

    // workspace layout (16B aligned blocks); xpb/asrc have +1 sentinel row
    unsigned short* xpb  = (unsigned short*)d_ws;             // (NT+1)*D1 bf16
    unsigned short* xhi  = xpb  + (size_t)(NT + 1) * D1;      // NT*FIN
    unsigned short* xlo  = xhi  + (size_t)NT * FIN;           // NT*FIN
    unsigned short* h1hi = xlo  + (size_t)NT * FIN;           // NT*D1
    unsigned short* h1lo = h1hi + (size_t)NT * D1;            // NT*D1
    float*    asrc   = (float*)(h1lo + (size_t)NT * D1);      // (NT+1)*H
    float*    adst   = asrc + (size_t)(NT + 1) * H;           // NT*H
    unsigned short* pB1 = (unsigned short*)(adst + (size_t)NT * H); // 4*18*64*8
    unsigned short* pB2 = pB1 + (size_t)4 * NSLOT * 64 * 8;         // 8*18*64*8
    unsigned* cnt    = (unsigned*)(pB2 + (size_t)8 * NSLOT * 64 * 8); // NT
    int*      slots  = (int*)(cnt + NT);                      // NT*CAP

    // 6 dispatches total
    k_zero<<<NT / 256, 256, 0, stream>>>(cnt, asrc, xpb);
    k_combo<<<54 + NT / 8, 256, 0, stream>>>(x, ei, xhi, xlo, out, cnt, slots,
                                             W1, as1, ad1, W2, as2, ad2, pB1, pB2);

    // ---------------- layer 1 (K = 128) ----------------
    k_mfma<128, true><<<NT / 64 + NT / 256, 256, 0, stream>>>(
        xhi, xlo, pB1, xpb, asrc, adst, cnt, slots);
    k_node<<<NT / 4, 256, 0, stream>>>(cnt, slots, asrc, adst, xpb,
                                       b1, pw1, pb1, h1hi, h1lo, out, 1);

    // ---------------- layer 2 (K = 256) ----------------
    k_mfma<256, false><<<NT / 64, 256, 0, stream>>>(
        h1hi, h1lo, pB2, xpb, asrc, adst, cnt, slots);
    k_node<<<NT / 4, 256, 0, stream>>>(cnt, slots, asrc, adst, xpb,
                                       b2, pw2, pb2, nullptr, nullptr, out, 2);
}